// Round 1
// baseline (12246.651 us; speedup 1.0000x reference)
//
#include <hip/hip_runtime.h>

// B=2, streams=2, N=1024, D=256, H=4, DH=64, L=18
// Row layout for all activation buffers: r = s*2048 + b*1024 + n  (M=4096 rows)

#define MROWS 4096

// ---------- copy with (s,b) swap: bits 18 (b/s) and 19 (s/b) of float index
__global__ __launch_bounds__(256) void swap_copy(const float* __restrict__ src,
                                                 float* __restrict__ dst) {
  int idx = blockIdx.x * 256 + threadIdx.x;   // float4 index, 262144 total
  int fi = idx << 2;
  int hi = (fi >> 19) & 1;
  int lo = (fi >> 18) & 1;
  int sj = (fi & ~(3 << 18)) | (lo << 19) | (hi << 18);
  *(float4*)&dst[fi] = *(const float4*)&src[sj];
}

// ---------- generic 64x64-tile fp32 GEMM body (256 threads, 4x4 microtile, KT=16)
__device__ __forceinline__ void gemm_body(const float* __restrict__ At, int lda,
                                          const float* __restrict__ A2t,
                                          const float* __restrict__ W, int ldw,
                                          const float* __restrict__ bias,
                                          float* __restrict__ Ct, int ldc,
                                          int K, bool accum) {
  __shared__ float As[16][64];
  __shared__ float Bs[16][64];
  const int tid = threadIdx.x;
  const int tx = tid & 15, ty = tid >> 4;
  const int a_r = tid >> 2;
  const int a_k = (tid & 3) << 2;
  const int b_k = tid >> 4;
  const int b_n = (tid & 15) << 2;
  float acc[4][4];
#pragma unroll
  for (int i = 0; i < 4; ++i)
#pragma unroll
    for (int j = 0; j < 4; ++j) acc[i][j] = 0.f;

  for (int k0 = 0; k0 < K; k0 += 16) {
    const float* Ap = At;
    int kb = k0;
    if (A2t != nullptr && k0 >= 256) { Ap = A2t; kb = k0 - 256; }
    float4 av = *(const float4*)&Ap[a_r * lda + kb + a_k];
    float4 bv = *(const float4*)&W[(k0 + b_k) * ldw + b_n];
    __syncthreads();
    As[a_k + 0][a_r] = av.x;
    As[a_k + 1][a_r] = av.y;
    As[a_k + 2][a_r] = av.z;
    As[a_k + 3][a_r] = av.w;
    *(float4*)&Bs[b_k][b_n] = bv;
    __syncthreads();
#pragma unroll
    for (int kk = 0; kk < 16; ++kk) {
      float4 a4 = *(const float4*)&As[kk][ty << 2];
      float4 b4 = *(const float4*)&Bs[kk][tx << 2];
      float aa[4] = {a4.x, a4.y, a4.z, a4.w};
      float bb[4] = {b4.x, b4.y, b4.z, b4.w};
#pragma unroll
      for (int i = 0; i < 4; ++i)
#pragma unroll
        for (int j = 0; j < 4; ++j) acc[i][j] += aa[i] * bb[j];
    }
  }
  float4 bv4 = *(const float4*)&bias[tx << 2];
  float bb[4] = {bv4.x, bv4.y, bv4.z, bv4.w};
#pragma unroll
  for (int i = 0; i < 4; ++i) {
    float* crow = Ct + (ty * 4 + i) * ldc + (tx << 2);
#pragma unroll
    for (int j = 0; j < 4; ++j) {
      float val = acc[i][j] + bb[j];
      if (accum) crow[j] += val; else crow[j] = val;
    }
  }
}

// ---------- QKV: q = x@qw+qb ; k/v = src@{kw,vw}+{kb,vb} with cross-stream src map
__global__ __launch_bounds__(256) void qkv_gemm(
    const float* __restrict__ xd,
    const float* __restrict__ qw, const float* __restrict__ qb,
    const float* __restrict__ kw, const float* __restrict__ kb,
    const float* __restrict__ vw, const float* __restrict__ vb,
    float* __restrict__ q, float* __restrict__ k, float* __restrict__ v,
    int cross) {
  int rb = blockIdx.x * 64, cb = blockIdx.y * 64, which = blockIdx.z;
  int arb = rb;
  const float* W; const float* bias; float* C;
  if (which == 0) { W = qw; bias = qb; C = q; }
  else {
    arb = (rb & 2047) | ((((rb >> 11) ^ cross) & 1) << 11);
    if (which == 1) { W = kw; bias = kb; C = k; }
    else            { W = vw; bias = vb; C = v; }
  }
  gemm_body(xd + (size_t)arb * 256, 256, nullptr, W + cb, 256, bias + cb,
            C + (size_t)rb * 256 + cb, 256, 256, false);
}

// ---------- generic GEMM (optional concat A2 for k>=256, optional accumulate)
__global__ __launch_bounds__(256) void gemm_kernel(
    const float* __restrict__ A, int lda, const float* __restrict__ A2,
    const float* __restrict__ W, int ldw, const float* __restrict__ bias,
    float* __restrict__ C, int ldc, int K, int accum) {
  int rb = blockIdx.x * 64, cb = blockIdx.y * 64;
  gemm_body(A + (size_t)rb * lda, lda, A2 ? A2 + (size_t)rb * 256 : nullptr,
            W + cb, ldw, bias + cb, C + (size_t)rb * ldc + cb, ldc, K, accum != 0);
}

// ---------- attention: 1 thread per query, online softmax, 64-key LDS tiles
__global__ __launch_bounds__(256) void attn_kernel(
    const float* __restrict__ q, const float* __restrict__ k,
    const float* __restrict__ v, const int* __restrict__ mask,
    float* __restrict__ attn, int cross) {
  __shared__ float Ks[64][64];
  __shared__ float Vs[64][64];
  __shared__ float Ms[64];   // 1.0 if masked-out, 0.0 otherwise
  const int tid = threadIdx.x;
  const int qt = blockIdx.x;   // 0..3  (256 queries each)
  const int h  = blockIdx.y;   // 0..3
  const int sb = blockIdx.z;   // s*2+b, 0..3
  const int s = sb >> 1, b = sb & 1;
  const int rowbase = sb * 1024;
  const int n = qt * 256 + tid;

  const float* qp = q + (size_t)(rowbase + n) * 256 + h * 64;
  float qreg[64];
#pragma unroll
  for (int j = 0; j < 64; ++j) qreg[j] = qp[j];
  float o[64];
#pragma unroll
  for (int j = 0; j < 64; ++j) o[j] = 0.f;
  float mrun = -1e30f, l = 0.f;
  const int* mp = mask + (b * 2 + (s ^ cross)) * 1024;
  const float scale = 0.125f;   // 1/sqrt(64)

  for (int m0 = 0; m0 < 1024; m0 += 64) {
    __syncthreads();
    {
      int rr = tid >> 2;
      int cc = (tid & 3) * 16;
      const float* kp = k + (size_t)(rowbase + m0 + rr) * 256 + h * 64 + cc;
      const float* vp = v + (size_t)(rowbase + m0 + rr) * 256 + h * 64 + cc;
#pragma unroll
      for (int i = 0; i < 4; ++i) {
        *(float4*)&Ks[rr][cc + i * 4] = *(const float4*)&kp[i * 4];
        *(float4*)&Vs[rr][cc + i * 4] = *(const float4*)&vp[i * 4];
      }
      if (tid < 64) Ms[tid] = (mp[m0 + tid] == 0) ? 1.f : 0.f;
    }
    __syncthreads();

    for (int c0 = 0; c0 < 64; c0 += 8) {
      float p[8];
#pragma unroll
      for (int u = 0; u < 8; ++u) {
        float acc = 0.f;
#pragma unroll
        for (int j = 0; j < 64; ++j) acc += qreg[j] * Ks[c0 + u][j];
        acc *= scale;
        p[u] = (Ms[c0 + u] > 0.5f) ? -1.0e9f : acc;
      }
      float cmax = p[0];
#pragma unroll
      for (int u = 1; u < 8; ++u) cmax = fmaxf(cmax, p[u]);
      float mnew = fmaxf(mrun, cmax);
      float corr = __expf(mrun - mnew);
      l *= corr;
#pragma unroll
      for (int j = 0; j < 64; ++j) o[j] *= corr;
#pragma unroll
      for (int u = 0; u < 8; ++u) {
        float e = __expf(p[u] - mnew);
        l += e;
#pragma unroll
        for (int j = 0; j < 64; ++j) o[j] += e * Vs[c0 + u][j];
      }
      mrun = mnew;
    }
  }
  float inv = 1.f / l;
  float* ap = attn + (size_t)(rowbase + n) * 256 + h * 64;
#pragma unroll
  for (int j = 0; j < 64; ++j) ap[j] = o[j] * inv;
}

// ---------- BatchNorm: two-stage deterministic reduction over 2048 rows/stream
__global__ __launch_bounds__(256) void bn_partial(const float* __restrict__ h,
                                                  float* __restrict__ psum,
                                                  float* __restrict__ psq) {
  int t = threadIdx.x;          // 256
  int rc = blockIdx.x;          // 0..7 row chunks of 256
  int cg = blockIdx.y;          // 0..1 channel halves
  int s  = blockIdx.z;          // 0..1 streams
  int c = cg * 256 + t;
  const float* hp = h + (size_t)(s * 2048 + rc * 256) * 512 + c;
  float sum = 0.f, sq = 0.f;
#pragma unroll 4
  for (int i = 0; i < 256; ++i) {
    float x = hp[(size_t)i * 512];
    sum += x; sq += x * x;
  }
  psum[(s * 8 + rc) * 512 + c] = sum;
  psq [(s * 8 + rc) * 512 + c] = sq;
}

__global__ __launch_bounds__(1024) void bn_finalize(const float* __restrict__ psum,
                                                    const float* __restrict__ psq,
                                                    const float* __restrict__ g,
                                                    const float* __restrict__ be,
                                                    float* __restrict__ scale,
                                                    float* __restrict__ shift) {
  int t = threadIdx.x;          // 1024
  int s = t >> 9, c = t & 511;
  float sum = 0.f, sq = 0.f;
  for (int rc = 0; rc < 8; ++rc) {
    sum += psum[(s * 8 + rc) * 512 + c];
    sq  += psq [(s * 8 + rc) * 512 + c];
  }
  float mean = sum * (1.f / 2048.f);
  float var = sq * (1.f / 2048.f) - mean * mean;
  float rstd = rsqrtf(var + 1e-5f);
  float gs = g[c] * rstd;
  scale[s * 512 + c] = gs;
  shift[s * 512 + c] = be[c] - mean * gs;
}

__global__ __launch_bounds__(256) void bn_apply(float* __restrict__ h,
                                                const float* __restrict__ scale,
                                                const float* __restrict__ shift) {
  int idx = blockIdx.x * 256 + threadIdx.x;   // float4 index over 2^21/4
  int fi = idx << 2;
  int c = fi & 511;
  int r = fi >> 9;
  int s = r >> 11;
  float4 hv = *(float4*)&h[fi];
  float4 sc = *(const float4*)&scale[s * 512 + c];
  float4 sh = *(const float4*)&shift[s * 512 + c];
  hv.x = fmaxf(hv.x * sc.x + sh.x, 0.f);
  hv.y = fmaxf(hv.y * sc.y + sh.y, 0.f);
  hv.z = fmaxf(hv.z * sc.z + sh.z, 0.f);
  hv.w = fmaxf(hv.w * sc.w + sh.w, 0.f);
  *(float4*)&h[fi] = hv;
}

extern "C" void kernel_launch(void* const* d_in, const int* in_sizes, int n_in,
                              void* d_out, int out_size, void* d_ws, size_t ws_size,
                              hipStream_t stream) {
  (void)in_sizes; (void)n_in; (void)out_size; (void)ws_size;
  const float* desc = (const float*)d_in[0];
  const int*   mask = (const int*)d_in[1];
  const float* qw = (const float*)d_in[2];
  const float* qb = (const float*)d_in[3];
  const float* kw = (const float*)d_in[4];
  const float* kb = (const float*)d_in[5];
  const float* vw = (const float*)d_in[6];
  const float* vb = (const float*)d_in[7];
  const float* ow = (const float*)d_in[8];
  const float* ob = (const float*)d_in[9];
  const float* w1 = (const float*)d_in[10];
  const float* b1 = (const float*)d_in[11];
  const float* bn_g = (const float*)d_in[12];
  const float* bn_b = (const float*)d_in[13];
  const float* w2 = (const float*)d_in[14];
  const float* b2 = (const float*)d_in[15];
  float* out = (float*)d_out;

  float* ws = (float*)d_ws;
  float* xd   = ws;                       // 2^20 floats
  float* qbuf = ws + (1u << 20);
  float* kbuf = ws + (2u << 20);
  float* vbuf = ws + (3u << 20);
  float* attn = ws + (4u << 20);
  float* ao   = ws + (5u << 20);
  float* hbuf = ws + (6u << 20);          // 2^21 floats
  float* psum = ws + (8u << 20);          // 8192
  float* psq  = psum + 8192;              // 8192
  float* scaleB = psq + 8192;             // 1024
  float* shiftB = scaleB + 1024;          // 1024

  swap_copy<<<1024, 256, 0, stream>>>(desc, xd);

  for (int i = 0; i < 18; ++i) {
    int cross = i & 1;
    const float* qwL = qw + (size_t)i * 65536;
    const float* qbL = qb + (size_t)i * 256;
    const float* kwL = kw + (size_t)i * 65536;
    const float* kbL = kb + (size_t)i * 256;
    const float* vwL = vw + (size_t)i * 65536;
    const float* vbL = vb + (size_t)i * 256;
    const float* owL = ow + (size_t)i * 65536;
    const float* obL = ob + (size_t)i * 256;
    const float* w1L = w1 + (size_t)i * 262144;
    const float* b1L = b1 + (size_t)i * 512;
    const float* gL  = bn_g + (size_t)i * 512;
    const float* beL = bn_b + (size_t)i * 512;
    const float* w2L = w2 + (size_t)i * 131072;
    const float* b2L = b2 + (size_t)i * 256;

    qkv_gemm<<<dim3(64, 4, 3), 256, 0, stream>>>(xd, qwL, qbL, kwL, kbL, vwL, vbL,
                                                 qbuf, kbuf, vbuf, cross);
    attn_kernel<<<dim3(4, 4, 4), 256, 0, stream>>>(qbuf, kbuf, vbuf, mask, attn, cross);
    gemm_kernel<<<dim3(64, 4), 256, 0, stream>>>(attn, 256, nullptr, owL, 256, obL,
                                                 ao, 256, 256, 0);
    gemm_kernel<<<dim3(64, 8), 256, 0, stream>>>(xd, 256, ao, w1L, 512, b1L,
                                                 hbuf, 512, 512, 0);
    bn_partial<<<dim3(8, 2, 2), 256, 0, stream>>>(hbuf, psum, psq);
    bn_finalize<<<1, 1024, 0, stream>>>(psum, psq, gL, beL, scaleB, shiftB);
    bn_apply<<<2048, 256, 0, stream>>>(hbuf, scaleB, shiftB);
    gemm_kernel<<<dim3(64, 4), 256, 0, stream>>>(hbuf, 512, nullptr, w2L, 256, b2L,
                                                 xd, 256, 512, 1);
  }

  swap_copy<<<1024, 256, 0, stream>>>(xd, out);
}

// Round 2
// 6501.266 us; speedup vs baseline: 1.8837x; 1.8837x over previous
//
#include <hip/hip_runtime.h>

// B=2, streams=2, N=1024, D=256, H=4, DH=64, L=18
// Row layout for all activation buffers: r = s*2048 + b*1024 + n  (M=4096 rows)

// ---------- copy with (s,b) swap: bits 18 (b/s) and 19 (s/b) of float index
__global__ __launch_bounds__(256) void swap_copy(const float* __restrict__ src,
                                                 float* __restrict__ dst) {
  int idx = blockIdx.x * 256 + threadIdx.x;   // float4 index, 262144 total
  int fi = idx << 2;
  int hi = (fi >> 19) & 1;
  int lo = (fi >> 18) & 1;
  int sj = (fi & ~(3 << 18)) | (lo << 19) | (hi << 18);
  *(float4*)&dst[fi] = *(const float4*)&src[sj];
}

// ---------- generic 64x64-tile fp32 GEMM body (256 threads, 4x4 microtile, KT=16)
__device__ __forceinline__ void gemm_body(const float* __restrict__ At, int lda,
                                          const float* __restrict__ A2t,
                                          const float* __restrict__ W, int ldw,
                                          const float* __restrict__ bias,
                                          float* __restrict__ Ct, int ldc,
                                          int K, bool accum) {
  __shared__ float As[16][64];
  __shared__ float Bs[16][64];
  const int tid = threadIdx.x;
  const int tx = tid & 15, ty = tid >> 4;
  const int a_r = tid >> 2;
  const int a_k = (tid & 3) << 2;
  const int b_k = tid >> 4;
  const int b_n = (tid & 15) << 2;
  float acc[4][4];
#pragma unroll
  for (int i = 0; i < 4; ++i)
#pragma unroll
    for (int j = 0; j < 4; ++j) acc[i][j] = 0.f;

  for (int k0 = 0; k0 < K; k0 += 16) {
    const float* Ap = At;
    int kb = k0;
    if (A2t != nullptr && k0 >= 256) { Ap = A2t; kb = k0 - 256; }
    float4 av = *(const float4*)&Ap[a_r * lda + kb + a_k];
    float4 bv = *(const float4*)&W[(k0 + b_k) * ldw + b_n];
    __syncthreads();
    As[a_k + 0][a_r] = av.x;
    As[a_k + 1][a_r] = av.y;
    As[a_k + 2][a_r] = av.z;
    As[a_k + 3][a_r] = av.w;
    *(float4*)&Bs[b_k][b_n] = bv;
    __syncthreads();
#pragma unroll
    for (int kk = 0; kk < 16; ++kk) {
      float4 a4 = *(const float4*)&As[kk][ty << 2];
      float4 b4 = *(const float4*)&Bs[kk][tx << 2];
      float aa[4] = {a4.x, a4.y, a4.z, a4.w};
      float bb[4] = {b4.x, b4.y, b4.z, b4.w};
#pragma unroll
      for (int i = 0; i < 4; ++i)
#pragma unroll
        for (int j = 0; j < 4; ++j) acc[i][j] += aa[i] * bb[j];
    }
  }
  float4 bv4 = *(const float4*)&bias[tx << 2];
  float bb[4] = {bv4.x, bv4.y, bv4.z, bv4.w};
#pragma unroll
  for (int i = 0; i < 4; ++i) {
    float* crow = Ct + (ty * 4 + i) * ldc + (tx << 2);
#pragma unroll
    for (int j = 0; j < 4; ++j) {
      float val = acc[i][j] + bb[j];
      if (accum) crow[j] += val; else crow[j] = val;
    }
  }
}

// ---------- QKV: q = x@qw+qb ; k/v = src@{kw,vw}+{kb,vb} with cross-stream src map
__global__ __launch_bounds__(256) void qkv_gemm(
    const float* __restrict__ xd,
    const float* __restrict__ qw, const float* __restrict__ qb,
    const float* __restrict__ kw, const float* __restrict__ kb,
    const float* __restrict__ vw, const float* __restrict__ vb,
    float* __restrict__ q, float* __restrict__ k, float* __restrict__ v,
    int cross) {
  int rb = blockIdx.x * 64, cb = blockIdx.y * 64, which = blockIdx.z;
  int arb = rb;
  const float* W; const float* bias; float* C;
  if (which == 0) { W = qw; bias = qb; C = q; }
  else {
    arb = (rb & 2047) | ((((rb >> 11) ^ cross) & 1) << 11);
    if (which == 1) { W = kw; bias = kb; C = k; }
    else            { W = vw; bias = vb; C = v; }
  }
  gemm_body(xd + (size_t)arb * 256, 256, nullptr, W + cb, 256, bias + cb,
            C + (size_t)rb * 256 + cb, 256, 256, false);
}

// ---------- generic GEMM (optional concat A2 for k>=256, optional accumulate)
__global__ __launch_bounds__(256) void gemm_kernel(
    const float* __restrict__ A, int lda, const float* __restrict__ A2,
    const float* __restrict__ W, int ldw, const float* __restrict__ bias,
    float* __restrict__ C, int ldc, int K, int accum) {
  int rb = blockIdx.x * 64, cb = blockIdx.y * 64;
  gemm_body(A + (size_t)rb * lda, lda, A2 ? A2 + (size_t)rb * 256 : nullptr,
            W + cb, ldw, bias + cb, C + (size_t)rb * ldc + cb, ldc, K, accum != 0);
}

// ---------- attention, flash split-K partials
// Lane pair shares one query: lane holds 32 q-dims + 32 o-dims; full score via shfl.
// grid (qt=8, kc=2, z=16 [sb*4+h]); block 256. 128 queries/block, 512 keys/chunk.
__global__ __launch_bounds__(256) void attn_partial(
    const float* __restrict__ q, const float* __restrict__ k,
    const float* __restrict__ v, const int* __restrict__ mask,
    float* __restrict__ po, float* __restrict__ pm, float* __restrict__ pl,
    int cross) {
  __shared__ float Ks[64][68];   // pad 64->68: staging writes 2-way (free)
  __shared__ float Vs[64][68];
  __shared__ float Ms[64];       // 1.0 if masked-out
  const int tid = threadIdx.x;
  const int qt = blockIdx.x;     // 0..7
  const int kc = blockIdx.y;     // 0..1
  const int z  = blockIdx.z;     // 0..15 = sb*4 + h
  const int sb = z >> 2, h = z & 3;
  const int s = sb >> 1, b = sb & 1;
  const int rowbase = sb * 1024;
  const int p = tid >> 1;        // query within tile
  const int half = tid & 1;
  const int qi = qt * 128 + p;
  const int hb = half * 32;

  const float* qp = q + (size_t)(rowbase + qi) * 256 + h * 64 + hb;
  float qreg[32];
#pragma unroll
  for (int jj = 0; jj < 8; ++jj) {
    float4 t = *(const float4*)&qp[jj * 4];
    qreg[jj*4+0] = t.x; qreg[jj*4+1] = t.y; qreg[jj*4+2] = t.z; qreg[jj*4+3] = t.w;
  }
  float o[32];
#pragma unroll
  for (int j = 0; j < 32; ++j) o[j] = 0.f;
  float mrun = -1e30f, l = 0.f;
  const int* mp = mask + (b * 2 + (s ^ cross)) * 1024 + kc * 512;
  const float scale = 0.125f;    // 1/sqrt(64)

  for (int t0 = 0; t0 < 512; t0 += 64) {
    __syncthreads();
    {
      int rr = tid >> 2;
      int cc = (tid & 3) * 16;
      const float* kp = k + (size_t)(rowbase + kc * 512 + t0 + rr) * 256 + h * 64 + cc;
      const float* vp = v + (size_t)(rowbase + kc * 512 + t0 + rr) * 256 + h * 64 + cc;
#pragma unroll
      for (int i = 0; i < 4; ++i) {
        *(float4*)&Ks[rr][cc + i * 4] = *(const float4*)&kp[i * 4];
        *(float4*)&Vs[rr][cc + i * 4] = *(const float4*)&vp[i * 4];
      }
      if (tid < 64) Ms[tid] = (mp[t0 + tid] == 0) ? 1.f : 0.f;
    }
    __syncthreads();

    for (int c0 = 0; c0 < 64; c0 += 8) {
      float pv8[8];
#pragma unroll
      for (int u = 0; u < 8; ++u) {
        float acc = 0.f;
        const float* kr = &Ks[c0 + u][hb];
#pragma unroll
        for (int jj = 0; jj < 8; ++jj) {
          float4 kv = *(const float4*)&kr[jj * 4];
          acc += qreg[jj*4+0]*kv.x + qreg[jj*4+1]*kv.y
               + qreg[jj*4+2]*kv.z + qreg[jj*4+3]*kv.w;
        }
        acc += __shfl_xor(acc, 1);
        acc *= scale;
        pv8[u] = (Ms[c0 + u] > 0.5f) ? -1.0e9f : acc;
      }
      float cmax = pv8[0];
#pragma unroll
      for (int u = 1; u < 8; ++u) cmax = fmaxf(cmax, pv8[u]);
      float mnew = fmaxf(mrun, cmax);
      float corr = __expf(mrun - mnew);
      l *= corr;
#pragma unroll
      for (int j = 0; j < 32; ++j) o[j] *= corr;
#pragma unroll
      for (int u = 0; u < 8; ++u) {
        float e = __expf(pv8[u] - mnew);
        l += e;
        const float* vr = &Vs[c0 + u][hb];
#pragma unroll
        for (int jj = 0; jj < 8; ++jj) {
          float4 vv = *(const float4*)&vr[jj * 4];
          o[jj*4+0] += e * vv.x; o[jj*4+1] += e * vv.y;
          o[jj*4+2] += e * vv.z; o[jj*4+3] += e * vv.w;
        }
      }
      mrun = mnew;
    }
  }
  size_t pbase = ((size_t)(kc * 16 + z) * 1024 + qi) * 64 + hb;
#pragma unroll
  for (int jj = 0; jj < 8; ++jj) {
    float4 t; t.x = o[jj*4+0]; t.y = o[jj*4+1]; t.z = o[jj*4+2]; t.w = o[jj*4+3];
    *(float4*)&po[pbase + jj * 4] = t;
  }
  if (half == 0) {
    pm[(kc * 16 + z) * 1024 + qi] = mrun;
    pl[(kc * 16 + z) * 1024 + qi] = l;
  }
}

// ---------- exact combine of the 2 key-chunk partials -> attn buffer
__global__ __launch_bounds__(256) void attn_combine(
    const float* __restrict__ po, const float* __restrict__ pm,
    const float* __restrict__ pl, float* __restrict__ attn) {
  int idx = blockIdx.x * 256 + threadIdx.x;   // float4 over 16*1024*64 = 2^20
  int fi = idx << 2;
  int zq = fi >> 6;
  int d  = fi & 63;
  float m0 = pm[zq], m1 = pm[16384 + zq];
  float l0 = pl[zq], l1 = pl[16384 + zq];
  float m = fmaxf(m0, m1);
  float a0 = __expf(m0 - m), a1 = __expf(m1 - m);
  float linv = 1.f / (a0 * l0 + a1 * l1);
  float4 o0 = *(const float4*)&po[(size_t)zq * 64 + d];
  float4 o1 = *(const float4*)&po[(size_t)(16384 + zq) * 64 + d];
  int zz = zq >> 10, qq = zq & 1023;
  int sb = zz >> 2, h = zz & 3;
  float4 r;
  r.x = (a0 * o0.x + a1 * o1.x) * linv;
  r.y = (a0 * o0.y + a1 * o1.y) * linv;
  r.z = (a0 * o0.z + a1 * o1.z) * linv;
  r.w = (a0 * o0.w + a1 * o1.w) * linv;
  *(float4*)&attn[(size_t)(sb * 1024 + qq) * 256 + h * 64 + d] = r;
}

// ---------- BatchNorm: two-stage deterministic reduction over 2048 rows/stream
__global__ __launch_bounds__(256) void bn_partial(const float* __restrict__ h,
                                                  float* __restrict__ psum,
                                                  float* __restrict__ psq) {
  int t = threadIdx.x;          // 256
  int rc = blockIdx.x;          // 0..7 row chunks of 256
  int cg = blockIdx.y;          // 0..1 channel halves
  int s  = blockIdx.z;          // 0..1 streams
  int c = cg * 256 + t;
  const float* hp = h + (size_t)(s * 2048 + rc * 256) * 512 + c;
  float sum = 0.f, sq = 0.f;
#pragma unroll 4
  for (int i = 0; i < 256; ++i) {
    float x = hp[(size_t)i * 512];
    sum += x; sq += x * x;
  }
  psum[(s * 8 + rc) * 512 + c] = sum;
  psq [(s * 8 + rc) * 512 + c] = sq;
}

__global__ __launch_bounds__(1024) void bn_finalize(const float* __restrict__ psum,
                                                    const float* __restrict__ psq,
                                                    const float* __restrict__ g,
                                                    const float* __restrict__ be,
                                                    float* __restrict__ scale,
                                                    float* __restrict__ shift) {
  int t = threadIdx.x;          // 1024
  int s = t >> 9, c = t & 511;
  float sum = 0.f, sq = 0.f;
  for (int rc = 0; rc < 8; ++rc) {
    sum += psum[(s * 8 + rc) * 512 + c];
    sq  += psq [(s * 8 + rc) * 512 + c];
  }
  float mean = sum * (1.f / 2048.f);
  float var = sq * (1.f / 2048.f) - mean * mean;
  float rstd = rsqrtf(var + 1e-5f);
  float gs = g[c] * rstd;
  scale[s * 512 + c] = gs;
  shift[s * 512 + c] = be[c] - mean * gs;
}

__global__ __launch_bounds__(256) void bn_apply(float* __restrict__ h,
                                                const float* __restrict__ scale,
                                                const float* __restrict__ shift) {
  int idx = blockIdx.x * 256 + threadIdx.x;   // float4 index over 2^21/4
  int fi = idx << 2;
  int c = fi & 511;
  int r = fi >> 9;
  int s = r >> 11;
  float4 hv = *(float4*)&h[fi];
  float4 sc = *(const float4*)&scale[s * 512 + c];
  float4 sh = *(const float4*)&shift[s * 512 + c];
  hv.x = fmaxf(hv.x * sc.x + sh.x, 0.f);
  hv.y = fmaxf(hv.y * sc.y + sh.y, 0.f);
  hv.z = fmaxf(hv.z * sc.z + sh.z, 0.f);
  hv.w = fmaxf(hv.w * sc.w + sh.w, 0.f);
  *(float4*)&h[fi] = hv;
}

extern "C" void kernel_launch(void* const* d_in, const int* in_sizes, int n_in,
                              void* d_out, int out_size, void* d_ws, size_t ws_size,
                              hipStream_t stream) {
  (void)in_sizes; (void)n_in; (void)out_size; (void)ws_size;
  const float* desc = (const float*)d_in[0];
  const int*   mask = (const int*)d_in[1];
  const float* qw = (const float*)d_in[2];
  const float* qb = (const float*)d_in[3];
  const float* kw = (const float*)d_in[4];
  const float* kb = (const float*)d_in[5];
  const float* vw = (const float*)d_in[6];
  const float* vb = (const float*)d_in[7];
  const float* ow = (const float*)d_in[8];
  const float* ob = (const float*)d_in[9];
  const float* w1 = (const float*)d_in[10];
  const float* b1 = (const float*)d_in[11];
  const float* bn_g = (const float*)d_in[12];
  const float* bn_b = (const float*)d_in[13];
  const float* w2 = (const float*)d_in[14];
  const float* b2 = (const float*)d_in[15];
  float* out = (float*)d_out;

  float* ws = (float*)d_ws;
  float* xd   = ws;                       // 2^20 floats
  float* qbuf = ws + (1u << 20);
  float* kbuf = ws + (2u << 20);
  float* vbuf = ws + (3u << 20);
  float* attn = ws + (4u << 20);
  float* ao   = ws + (5u << 20);
  float* hbuf = ws + (6u << 20);          // 2^21 floats
  float* psum = ws + (8u << 20);          // 8192
  float* psq  = psum + 8192;              // 8192
  float* scaleB = psq + 8192;             // 1024
  float* shiftB = scaleB + 1024;          // 1024
  // attention partials overlay buffers that are dead during attention:
  float* po = hbuf;                       // 2*16*1024*64 = 2^21 floats
  float* pm = ao;                         // 32768 floats
  float* pl = ao + 32768;                 // 32768 floats

  swap_copy<<<1024, 256, 0, stream>>>(desc, xd);

  for (int i = 0; i < 18; ++i) {
    int cross = i & 1;
    const float* qwL = qw + (size_t)i * 65536;
    const float* qbL = qb + (size_t)i * 256;
    const float* kwL = kw + (size_t)i * 65536;
    const float* kbL = kb + (size_t)i * 256;
    const float* vwL = vw + (size_t)i * 65536;
    const float* vbL = vb + (size_t)i * 256;
    const float* owL = ow + (size_t)i * 65536;
    const float* obL = ob + (size_t)i * 256;
    const float* w1L = w1 + (size_t)i * 262144;
    const float* b1L = b1 + (size_t)i * 512;
    const float* gL  = bn_g + (size_t)i * 512;
    const float* beL = bn_b + (size_t)i * 512;
    const float* w2L = w2 + (size_t)i * 131072;
    const float* b2L = b2 + (size_t)i * 256;

    qkv_gemm<<<dim3(64, 4, 3), 256, 0, stream>>>(xd, qwL, qbL, kwL, kbL, vwL, vbL,
                                                 qbuf, kbuf, vbuf, cross);
    attn_partial<<<dim3(8, 2, 16), 256, 0, stream>>>(qbuf, kbuf, vbuf, mask,
                                                     po, pm, pl, cross);
    attn_combine<<<1024, 256, 0, stream>>>(po, pm, pl, attn);
    gemm_kernel<<<dim3(64, 4), 256, 0, stream>>>(attn, 256, nullptr, owL, 256, obL,
                                                 ao, 256, 256, 0);
    gemm_kernel<<<dim3(64, 8), 256, 0, stream>>>(xd, 256, ao, w1L, 512, b1L,
                                                 hbuf, 512, 512, 0);
    bn_partial<<<dim3(8, 2, 2), 256, 0, stream>>>(hbuf, psum, psq);
    bn_finalize<<<1, 1024, 0, stream>>>(psum, psq, gL, beL, scaleB, shiftB);
    bn_apply<<<2048, 256, 0, stream>>>(hbuf, scaleB, shiftB);
    gemm_kernel<<<dim3(64, 4), 256, 0, stream>>>(hbuf, 512, nullptr, w2L, 256, b2L,
                                                 xd, 256, 512, 1);
  }

  swap_copy<<<1024, 256, 0, stream>>>(xd, out);
}

// Round 3
// 1793.650 us; speedup vs baseline: 6.8278x; 3.6246x over previous
//
#include <hip/hip_runtime.h>

// B=2, streams=2, N=1024, D=256, H=4, DH=64, L=18
// Row layout for all activation buffers: r = s*2048 + b*1024 + n  (M=4096 rows)
// bf16 MFMA layouts (gfx950, 16x16x32):
//   A-frag: lane holds A[m=lane&15][k=quad*8+j], j=0..7  (one b128 from K-major LDS)
//   B-frag: lane holds B[k=quad*8+j][n=lane&15]
//   C/D   : col=lane&15, row=quad*4+reg

typedef __attribute__((ext_vector_type(8))) short bf16x8;   // 8 bf16 = 4 VGPRs
typedef __attribute__((ext_vector_type(4))) float floatx4;

__device__ __forceinline__ short f2b(float f) {   // fp32 -> bf16 RNE
  unsigned u = __builtin_bit_cast(unsigned, f);
  unsigned r = (u + 0x7FFFu + ((u >> 16) & 1u)) >> 16;
  return (short)r;
}
__device__ __forceinline__ unsigned pack2(float a, float b) {
  return (unsigned)(unsigned short)f2b(a) | ((unsigned)(unsigned short)f2b(b) << 16);
}

// ---------- input copy with (s,b) swap; writes fp32 residual + bf16 copy
__global__ __launch_bounds__(256) void swap_copy_in(const float* __restrict__ src,
                                                    float* __restrict__ xd,
                                                    short* __restrict__ xb) {
  int idx = blockIdx.x * 256 + threadIdx.x;   // float4 index, 262144 total
  int fi = idx << 2;
  int hi = (fi >> 19) & 1;
  int lo = (fi >> 18) & 1;
  int sj = (fi & ~(3 << 18)) | (lo << 19) | (hi << 18);
  float4 v = *(const float4*)&src[sj];
  *(float4*)&xd[fi] = v;
  uint2 uu; uu.x = pack2(v.x, v.y); uu.y = pack2(v.z, v.w);
  *(uint2*)&xb[fi] = uu;
}

__global__ __launch_bounds__(256) void swap_copy_out(const float* __restrict__ src,
                                                     float* __restrict__ dst) {
  int idx = blockIdx.x * 256 + threadIdx.x;
  int fi = idx << 2;
  int hi = (fi >> 19) & 1;
  int lo = (fi >> 18) & 1;
  int sj = (fi & ~(3 << 18)) | (lo << 19) | (hi << 18);
  *(float4*)&dst[fi] = *(const float4*)&src[sj];
}

// ---------- per-layer weight transpose + fp32->bf16 convert: Wt[n][k]
// wbuf layout (shorts): qwt@0 kwt@65536 vwt@131072 owt@196608 w1t@262144 w2t@524288
__global__ __launch_bounds__(256) void wconv(
    const float* __restrict__ qw, const float* __restrict__ kw,
    const float* __restrict__ vw, const float* __restrict__ ow,
    const float* __restrict__ w1, const float* __restrict__ w2,
    short* __restrict__ wbuf) {
  __shared__ float T[64][65];
  int blk = blockIdx.x;
  const float* W; int Kd, Nd, k0, n0, ooff;
  if (blk < 64) {
    int wsel = blk >> 4; int t = blk & 15;
    k0 = (t >> 2) * 64; n0 = (t & 3) * 64; Kd = 256; Nd = 256;
    W = wsel == 0 ? qw : wsel == 1 ? kw : wsel == 2 ? vw : ow;
    ooff = wsel * 65536;
  } else if (blk < 128) {
    int t = blk - 64; k0 = (t >> 3) * 64; n0 = (t & 7) * 64;
    Kd = 512; Nd = 512; W = w1; ooff = 262144;
  } else {
    int t = blk - 128; k0 = (t >> 2) * 64; n0 = (t & 3) * 64;
    Kd = 512; Nd = 256; W = w2; ooff = 524288;
  }
  int t = threadIdx.x;
  int r = t >> 4, c4 = (t & 15) * 4;
#pragma unroll
  for (int rr = 0; rr < 4; ++rr) {
    float4 v = *(const float4*)&W[(size_t)(k0 + r + rr * 16) * Nd + n0 + c4];
    T[r + rr * 16][c4 + 0] = v.x; T[r + rr * 16][c4 + 1] = v.y;
    T[r + rr * 16][c4 + 2] = v.z; T[r + rr * 16][c4 + 3] = v.w;
  }
  __syncthreads();
  int n = t >> 2, kc = (t & 3) * 16;
  unsigned u[8];
#pragma unroll
  for (int j2 = 0; j2 < 8; ++j2)
    u[j2] = pack2(T[kc + 2 * j2][n], T[kc + 2 * j2 + 1][n]);
  short* op = &wbuf[(size_t)ooff + (size_t)(n0 + n) * Kd + k0 + kc];
  uint4 o1; o1.x = u[0]; o1.y = u[1]; o1.z = u[2]; o1.w = u[3];
  uint4 o2; o2.x = u[4]; o2.y = u[5]; o2.z = u[6]; o2.w = u[7];
  *(uint4*)&op[0] = o1;
  *(uint4*)&op[8] = o2;
}

// ---------- MFMA GEMM tile body: 64x64 tile, 4 waves (2x2), wave tile 32x32
// A bf16 [rows x K] row-major (tile-local base), optional A2 concat for k>=256.
// Wt bf16 [64 x K] (tile-local base, K-major). mode: 0=bf16 out, 1=fp32 out, 2=fp32 accum + bf16 copy
__device__ __forceinline__ void gemm_mfma_body(
    const short* __restrict__ A, int lda, const short* __restrict__ A2,
    const short* __restrict__ Wt, const float* __restrict__ bias,
    float* __restrict__ Cf, short* __restrict__ Cb, int ldc, int K, int mode) {
  __shared__ short As[64][72];
  __shared__ short Bs[64][72];
  const int tid = threadIdx.x;
  const int lane = tid & 63, w = tid >> 6;
  const int wy = w >> 1, wx = w & 1;
  const int quad = lane >> 4, l16 = lane & 15;
  const floatx4 zero4 = {0.f, 0.f, 0.f, 0.f};
  floatx4 acc[2][2] = {{zero4, zero4}, {zero4, zero4}};

  const int ar0 = tid >> 3, ak0 = (tid & 7) * 8;
  const int ar1 = ar0 + 32;

  for (int k0 = 0; k0 < K; k0 += 64) {
    const short* Ap = A; int kb = k0;
    if (A2 != nullptr && k0 >= 256) { Ap = A2; kb = k0 - 256; }
    uint4 av0 = *(const uint4*)&Ap[(size_t)ar0 * lda + kb + ak0];
    uint4 av1 = *(const uint4*)&Ap[(size_t)ar1 * lda + kb + ak0];
    uint4 bv0 = *(const uint4*)&Wt[(size_t)ar0 * K + k0 + ak0];
    uint4 bv1 = *(const uint4*)&Wt[(size_t)ar1 * K + k0 + ak0];
    __syncthreads();
    *(uint4*)&As[ar0][ak0] = av0;
    *(uint4*)&As[ar1][ak0] = av1;
    *(uint4*)&Bs[ar0][ak0] = bv0;
    *(uint4*)&Bs[ar1][ak0] = bv1;
    __syncthreads();
#pragma unroll
    for (int kk = 0; kk < 2; ++kk) {
      bf16x8 af0 = *(const bf16x8*)&As[wy * 32 + l16][kk * 32 + quad * 8];
      bf16x8 af1 = *(const bf16x8*)&As[wy * 32 + 16 + l16][kk * 32 + quad * 8];
      bf16x8 bf0 = *(const bf16x8*)&Bs[wx * 32 + l16][kk * 32 + quad * 8];
      bf16x8 bf1 = *(const bf16x8*)&Bs[wx * 32 + 16 + l16][kk * 32 + quad * 8];
      acc[0][0] = __builtin_amdgcn_mfma_f32_16x16x32_bf16(af0, bf0, acc[0][0], 0, 0, 0);
      acc[0][1] = __builtin_amdgcn_mfma_f32_16x16x32_bf16(af0, bf1, acc[0][1], 0, 0, 0);
      acc[1][0] = __builtin_amdgcn_mfma_f32_16x16x32_bf16(af1, bf0, acc[1][0], 0, 0, 0);
      acc[1][1] = __builtin_amdgcn_mfma_f32_16x16x32_bf16(af1, bf1, acc[1][1], 0, 0, 0);
    }
  }
#pragma unroll
  for (int mi = 0; mi < 2; ++mi)
#pragma unroll
    for (int ni = 0; ni < 2; ++ni) {
      int col = wx * 32 + ni * 16 + l16;
      float bcol = bias[col];
#pragma unroll
      for (int reg = 0; reg < 4; ++reg) {
        int row = wy * 32 + mi * 16 + quad * 4 + reg;
        float val = acc[mi][ni][reg] + bcol;
        size_t off = (size_t)row * ldc + col;
        if (mode == 0) Cb[off] = f2b(val);
        else if (mode == 1) Cf[off] = val;
        else { float nv = Cf[off] + val; Cf[off] = nv; Cb[off] = f2b(nv); }
      }
    }
}

// ---------- QKV (bf16): q = xb@qw+qb ; k/v = src@{kw,vw} with cross-stream src map
__global__ __launch_bounds__(256) void qkv_gemm(
    const short* __restrict__ xb, const short* __restrict__ wbuf,
    const float* __restrict__ qb_, const float* __restrict__ kb_,
    const float* __restrict__ vb_,
    short* __restrict__ q, short* __restrict__ k, short* __restrict__ v,
    int cross) {
  int rb = blockIdx.x * 64, cb = blockIdx.y * 64, which = blockIdx.z;
  int arb = rb;
  const short* Wt; const float* bias; short* C;
  if (which == 0) { Wt = wbuf; bias = qb_; C = q; }
  else {
    arb = (rb & 2047) | ((((rb >> 11) ^ cross) & 1) << 11);
    if (which == 1) { Wt = wbuf + 65536; bias = kb_; C = k; }
    else            { Wt = wbuf + 131072; bias = vb_; C = v; }
  }
  gemm_mfma_body(xb + (size_t)arb * 256, 256, nullptr,
                 Wt + (size_t)cb * 256, bias + cb,
                 nullptr, C + (size_t)rb * 256 + cb, 256, 256, 0);
}

// ---------- generic MFMA GEMM
__global__ __launch_bounds__(256) void gemm_bf16(
    const short* __restrict__ A, int lda, const short* __restrict__ A2,
    const short* __restrict__ Wt, const float* __restrict__ bias,
    float* __restrict__ Cf, short* __restrict__ Cb, int ldc, int K, int mode) {
  int rb = blockIdx.x * 64, cb = blockIdx.y * 64;
  gemm_mfma_body(A + (size_t)rb * lda, lda,
                 A2 ? A2 + (size_t)rb * 256 : nullptr,
                 Wt + (size_t)cb * K, bias + cb,
                 Cf ? Cf + (size_t)rb * ldc + cb : nullptr,
                 Cb ? Cb + (size_t)rb * ldc + cb : nullptr, ldc, K, mode);
}

// ---------- MFMA flash attention, split-K partials
// grid (qt=16, kc=2, z=16 [sb*4+h]); block 256 (4 waves); wave = 16 queries.
__global__ __launch_bounds__(256) void attn_mfma(
    const short* __restrict__ q, const short* __restrict__ k,
    const short* __restrict__ v, const int* __restrict__ mask,
    float* __restrict__ po, float* __restrict__ pm, float* __restrict__ pl,
    int cross) {
  __shared__ short Ks[64][72];      // [key][dim]
  __shared__ short Vt[64][72];      // [dim][key]
  __shared__ short Pw[4][16][72];   // per-wave P tile [query][key]
  __shared__ float Ms[64];          // additive mask (0 or -1e9)
  const int tid = threadIdx.x;
  const int lane = tid & 63, w = tid >> 6;
  const int quad = lane >> 4, l16 = lane & 15;
  const int qt = blockIdx.x;     // 0..15
  const int kc = blockIdx.y;     // 0..1
  const int z  = blockIdx.z;     // sb*4 + h
  const int sb = z >> 2, h = z & 3;
  const int s = sb >> 1, b = sb & 1;
  const int rowbase = sb * 1024;
  const int* maskbase = mask + (b * 2 + (s ^ cross)) * 1024 + kc * 512;

  // Q fragments (A-operand): lane m=l16, k contiguous
  const int qrow = qt * 64 + w * 16 + l16;
  bf16x8 qf[2];
#pragma unroll
  for (int kk = 0; kk < 2; ++kk)
    qf[kk] = *(const bf16x8*)&q[(size_t)(rowbase + qrow) * 256 + h * 64 + kk * 32 + quad * 8];

  const floatx4 zero4 = {0.f, 0.f, 0.f, 0.f};
  floatx4 o4[4] = {zero4, zero4, zero4, zero4};
  float mrun[4] = {-1e30f, -1e30f, -1e30f, -1e30f};
  float lsum[4] = {0.f, 0.f, 0.f, 0.f};

  const int sr = tid >> 3, scol = (tid & 7) * 8;   // staging: rows sr, sr+32

  for (int kt = 0; kt < 8; ++kt) {
    int key0 = kc * 512 + kt * 64;
    __syncthreads();
    // K tile [64][64] -> Ks (b128 writes)
    *(uint4*)&Ks[sr][scol]      = *(const uint4*)&k[(size_t)(rowbase + key0 + sr) * 256 + h * 64 + scol];
    *(uint4*)&Ks[sr + 32][scol] = *(const uint4*)&k[(size_t)(rowbase + key0 + sr + 32) * 256 + h * 64 + scol];
    // V tile transposed -> Vt[dim][key]
#pragma unroll
    for (int half = 0; half < 2; ++half) {
      int vr = sr + half * 32;
      uint4 vv = *(const uint4*)&v[(size_t)(rowbase + key0 + vr) * 256 + h * 64 + scol];
      unsigned uu[4] = {vv.x, vv.y, vv.z, vv.w};
#pragma unroll
      for (int j2 = 0; j2 < 4; ++j2) {
        Vt[scol + 2 * j2 + 0][vr] = (short)(uu[j2] & 0xffff);
        Vt[scol + 2 * j2 + 1][vr] = (short)(uu[j2] >> 16);
      }
    }
    if (tid < 64) Ms[tid] = (maskbase[kt * 64 + tid] == 0) ? -1.0e9f : 0.f;
    __syncthreads();

    // S = Q K^T : 4 key-tiles of 16
    floatx4 sA[4] = {zero4, zero4, zero4, zero4};
#pragma unroll
    for (int kk = 0; kk < 2; ++kk)
#pragma unroll
      for (int nt = 0; nt < 4; ++nt) {
        bf16x8 kf = *(const bf16x8*)&Ks[nt * 16 + l16][kk * 32 + quad * 8];
        sA[nt] = __builtin_amdgcn_mfma_f32_16x16x32_bf16(qf[kk], kf, sA[nt], 0, 0, 0);
      }
    float scv[4][4];
#pragma unroll
    for (int nt = 0; nt < 4; ++nt) {
      float mk = Ms[nt * 16 + l16];
#pragma unroll
      for (int reg = 0; reg < 4; ++reg) scv[nt][reg] = sA[nt][reg] * 0.125f + mk;
    }
    // row max across 16 lanes of the quad
    float rmx[4];
#pragma unroll
    for (int reg = 0; reg < 4; ++reg) {
      float m0 = fmaxf(fmaxf(scv[0][reg], scv[1][reg]), fmaxf(scv[2][reg], scv[3][reg]));
#pragma unroll
      for (int d = 1; d < 16; d <<= 1) m0 = fmaxf(m0, __shfl_xor(m0, d));
      rmx[reg] = m0;
    }
    // online softmax update + write P (bf16, per-wave LDS region)
#pragma unroll
    for (int reg = 0; reg < 4; ++reg) {
      float mnew = fmaxf(mrun[reg], rmx[reg]);
      float corr = __expf(mrun[reg] - mnew);
      mrun[reg] = mnew;
      lsum[reg] *= corr;
#pragma unroll
      for (int dt = 0; dt < 4; ++dt) o4[dt][reg] *= corr;
      float ps = 0.f;
#pragma unroll
      for (int nt = 0; nt < 4; ++nt) {
        float e = __expf(scv[nt][reg] - mnew);
        ps += e;
        Pw[w][quad * 4 + reg][nt * 16 + l16] = f2b(e);
      }
      lsum[reg] += ps;
    }
    // O += P V  (A = P from per-wave LDS, B = Vt)
#pragma unroll
    for (int kk = 0; kk < 2; ++kk) {
      bf16x8 pf = *(const bf16x8*)&Pw[w][l16][kk * 32 + quad * 8];
#pragma unroll
      for (int dt = 0; dt < 4; ++dt) {
        bf16x8 vf = *(const bf16x8*)&Vt[dt * 16 + l16][kk * 32 + quad * 8];
        o4[dt] = __builtin_amdgcn_mfma_f32_16x16x32_bf16(pf, vf, o4[dt], 0, 0, 0);
      }
    }
  }
  // reduce lsum across the 16 lanes (each lane summed 4 of 64 keys per row)
#pragma unroll
  for (int reg = 0; reg < 4; ++reg)
#pragma unroll
    for (int d = 1; d < 16; d <<= 1) lsum[reg] += __shfl_xor(lsum[reg], d);

  // store partials (unnormalized o, row max, row sum)
  int zq0 = (kc * 16 + z) * 1024;
#pragma unroll
  for (int reg = 0; reg < 4; ++reg) {
    int orow = qt * 64 + w * 16 + quad * 4 + reg;
#pragma unroll
    for (int dt = 0; dt < 4; ++dt)
      po[(size_t)(zq0 + orow) * 64 + dt * 16 + l16] = o4[dt][reg];
    if (l16 == 0) {
      pm[zq0 + orow] = mrun[reg];
      pl[zq0 + orow] = lsum[reg];
    }
  }
}

// ---------- exact combine of the 2 key-chunk partials -> attnb (bf16)
__global__ __launch_bounds__(256) void attn_combine(
    const float* __restrict__ po, const float* __restrict__ pm,
    const float* __restrict__ pl, short* __restrict__ attnb) {
  int idx = blockIdx.x * 256 + threadIdx.x;   // float4 over 16*1024*64 = 2^20
  int fi = idx << 2;
  int zq = fi >> 6;
  int d  = fi & 63;
  float m0 = pm[zq], m1 = pm[16384 + zq];
  float l0 = pl[zq], l1 = pl[16384 + zq];
  float m = fmaxf(m0, m1);
  float a0 = __expf(m0 - m), a1 = __expf(m1 - m);
  float linv = 1.f / (a0 * l0 + a1 * l1);
  float4 o0 = *(const float4*)&po[(size_t)zq * 64 + d];
  float4 o1 = *(const float4*)&po[(size_t)(16384 + zq) * 64 + d];
  int zz = zq >> 10, qq = zq & 1023;
  int sb = zz >> 2, h = zz & 3;
  float rx = (a0 * o0.x + a1 * o1.x) * linv;
  float ry = (a0 * o0.y + a1 * o1.y) * linv;
  float rz = (a0 * o0.z + a1 * o1.z) * linv;
  float rw = (a0 * o0.w + a1 * o1.w) * linv;
  uint2 uu; uu.x = pack2(rx, ry); uu.y = pack2(rz, rw);
  *(uint2*)&attnb[(size_t)(sb * 1024 + qq) * 256 + h * 64 + d] = uu;
}

// ---------- BatchNorm: two-stage deterministic reduction over 2048 rows/stream
__global__ __launch_bounds__(256) void bn_partial(const float* __restrict__ h,
                                                  float* __restrict__ psum,
                                                  float* __restrict__ psq) {
  int t = threadIdx.x;
  int rc = blockIdx.x;          // 0..7
  int cg = blockIdx.y;          // 0..1
  int s  = blockIdx.z;          // 0..1
  int c = cg * 256 + t;
  const float* hp = h + (size_t)(s * 2048 + rc * 256) * 512 + c;
  float sum = 0.f, sq = 0.f;
#pragma unroll 4
  for (int i = 0; i < 256; ++i) {
    float x = hp[(size_t)i * 512];
    sum += x; sq += x * x;
  }
  psum[(s * 8 + rc) * 512 + c] = sum;
  psq [(s * 8 + rc) * 512 + c] = sq;
}

__global__ __launch_bounds__(1024) void bn_finalize(const float* __restrict__ psum,
                                                    const float* __restrict__ psq,
                                                    const float* __restrict__ g,
                                                    const float* __restrict__ be,
                                                    float* __restrict__ scale,
                                                    float* __restrict__ shift) {
  int t = threadIdx.x;
  int s = t >> 9, c = t & 511;
  float sum = 0.f, sq = 0.f;
  for (int rc = 0; rc < 8; ++rc) {
    sum += psum[(s * 8 + rc) * 512 + c];
    sq  += psq [(s * 8 + rc) * 512 + c];
  }
  float mean = sum * (1.f / 2048.f);
  float var = sq * (1.f / 2048.f) - mean * mean;
  float rstd = rsqrtf(var + 1e-5f);
  float gs = g[c] * rstd;
  scale[s * 512 + c] = gs;
  shift[s * 512 + c] = be[c] - mean * gs;
}

// ---------- BN apply + ReLU: fp32 h -> bf16 hb
__global__ __launch_bounds__(256) void bn_apply(const float* __restrict__ h,
                                                short* __restrict__ hb,
                                                const float* __restrict__ scale,
                                                const float* __restrict__ shift) {
  int idx = blockIdx.x * 256 + threadIdx.x;
  int fi = idx << 2;
  int c = fi & 511;
  int r = fi >> 9;
  int s = r >> 11;
  float4 hv = *(const float4*)&h[fi];
  float4 sc = *(const float4*)&scale[s * 512 + c];
  float4 sh = *(const float4*)&shift[s * 512 + c];
  float rx = fmaxf(hv.x * sc.x + sh.x, 0.f);
  float ry = fmaxf(hv.y * sc.y + sh.y, 0.f);
  float rz = fmaxf(hv.z * sc.z + sh.z, 0.f);
  float rw = fmaxf(hv.w * sc.w + sh.w, 0.f);
  uint2 uu; uu.x = pack2(rx, ry); uu.y = pack2(rz, rw);
  *(uint2*)&hb[fi] = uu;
}

extern "C" void kernel_launch(void* const* d_in, const int* in_sizes, int n_in,
                              void* d_out, int out_size, void* d_ws, size_t ws_size,
                              hipStream_t stream) {
  (void)in_sizes; (void)n_in; (void)out_size; (void)ws_size;
  const float* desc = (const float*)d_in[0];
  const int*   mask = (const int*)d_in[1];
  const float* qw = (const float*)d_in[2];
  const float* qb = (const float*)d_in[3];
  const float* kw = (const float*)d_in[4];
  const float* kb = (const float*)d_in[5];
  const float* vw = (const float*)d_in[6];
  const float* vb = (const float*)d_in[7];
  const float* ow = (const float*)d_in[8];
  const float* ob = (const float*)d_in[9];
  const float* w1 = (const float*)d_in[10];
  const float* b1 = (const float*)d_in[11];
  const float* bn_g = (const float*)d_in[12];
  const float* bn_b = (const float*)d_in[13];
  const float* w2 = (const float*)d_in[14];
  const float* b2 = (const float*)d_in[15];
  float* out = (float*)d_out;

  char* base = (char*)d_ws;
  float* xd   = (float*)(base);                   // 1M fp32   [0, 4MB)
  float* hbuf = (float*)(base + (4u << 20));      // 2M fp32   [4, 12MB)
  float* po   = hbuf;                             // overlay (attention partials)
  float* psum = (float*)(base + (12u << 20));     // 8192
  float* psq    = psum + 8192;
  float* scaleB = psq + 8192;
  float* shiftB = scaleB + 1024;
  float* pm     = shiftB + 1024;                  // 32768
  float* pl     = pm + 32768;                     // 32768
  short* xb    = (short*)(base + (13u << 20));    // 1M bf16
  short* qb16  = (short*)(base + (15u << 20));
  short* kb16  = (short*)(base + (17u << 20));
  short* vb16  = (short*)(base + (19u << 20));
  short* attnb = (short*)(base + (21u << 20));
  short* aob   = (short*)(base + (23u << 20));
  short* hb    = (short*)(base + (25u << 20));    // 2M bf16
  short* wbuf  = (short*)(base + (29u << 20));    // 655360 bf16

  swap_copy_in<<<1024, 256, 0, stream>>>(desc, xd, xb);

  for (int i = 0; i < 18; ++i) {
    int cross = i & 1;
    const float* qwL = qw + (size_t)i * 65536;
    const float* qbL = qb + (size_t)i * 256;
    const float* kwL = kw + (size_t)i * 65536;
    const float* kbL = kb + (size_t)i * 256;
    const float* vwL = vw + (size_t)i * 65536;
    const float* vbL = vb + (size_t)i * 256;
    const float* owL = ow + (size_t)i * 65536;
    const float* obL = ob + (size_t)i * 256;
    const float* w1L = w1 + (size_t)i * 262144;
    const float* b1L = b1 + (size_t)i * 512;
    const float* gL  = bn_g + (size_t)i * 512;
    const float* beL = bn_b + (size_t)i * 512;
    const float* w2L = w2 + (size_t)i * 131072;
    const float* b2L = b2 + (size_t)i * 256;

    wconv<<<160, 256, 0, stream>>>(qwL, kwL, vwL, owL, w1L, w2L, wbuf);
    qkv_gemm<<<dim3(64, 4, 3), 256, 0, stream>>>(xb, wbuf, qbL, kbL, vbL,
                                                 qb16, kb16, vb16, cross);
    attn_mfma<<<dim3(16, 2, 16), 256, 0, stream>>>(qb16, kb16, vb16, mask,
                                                   po, pm, pl, cross);
    attn_combine<<<1024, 256, 0, stream>>>(po, pm, pl, attnb);
    gemm_bf16<<<dim3(64, 4), 256, 0, stream>>>(attnb, 256, nullptr,
                                               wbuf + 196608, obL,
                                               nullptr, aob, 256, 256, 0);
    gemm_bf16<<<dim3(64, 8), 256, 0, stream>>>(xb, 256, aob,
                                               wbuf + 262144, b1L,
                                               hbuf, nullptr, 512, 512, 1);
    bn_partial<<<dim3(8, 2, 2), 256, 0, stream>>>(hbuf, psum, psq);
    bn_finalize<<<1, 1024, 0, stream>>>(psum, psq, gL, beL, scaleB, shiftB);
    bn_apply<<<2048, 256, 0, stream>>>(hbuf, hb, scaleB, shiftB);
    gemm_bf16<<<dim3(64, 4), 256, 0, stream>>>(hb, 512, nullptr,
                                               wbuf + 524288, b2L,
                                               xd, xb, 256, 512, 2);
  }

  swap_copy_out<<<1024, 256, 0, stream>>>(xd, out);
}

// Round 4
// 1511.437 us; speedup vs baseline: 8.1027x; 1.1867x over previous
//
#include <hip/hip_runtime.h>

// B=2, streams=2, N=1024, D=256, H=4, DH=64, L=18
// Row layout: r = s*2048 + b*1024 + n  (M=4096 rows)
// bf16 MFMA 16x16x32: A-frag lane=A[m=lane&15][k=quad*8+j]; B-frag B[k=quad*8+j][n=lane&15]
// C/D: col=lane&15, row=quad*4+reg

typedef __attribute__((ext_vector_type(8))) short bf16x8;
typedef __attribute__((ext_vector_type(4))) float floatx4;

__device__ __forceinline__ short f2b(float f) {   // fp32 -> bf16 RNE
  unsigned u = __builtin_bit_cast(unsigned, f);
  unsigned r = (u + 0x7FFFu + ((u >> 16) & 1u)) >> 16;
  return (short)r;
}
__device__ __forceinline__ unsigned pack2(float a, float b) {
  return (unsigned)(unsigned short)f2b(a) | ((unsigned)(unsigned short)f2b(b) << 16);
}

// async global->LDS, 16B per lane. LDS dst = wave-uniform base + lane*16.
__device__ __forceinline__ void gl2lds16(const void* g, void* l) {
  __builtin_amdgcn_global_load_lds(
      (const __attribute__((address_space(1))) unsigned*)g,
      (__attribute__((address_space(3))) unsigned*)l, 16, 0, 0);
}

// ---------- input copy with (s,b) swap; writes fp32 residual + bf16 copy
__global__ __launch_bounds__(256) void swap_copy_in(const float* __restrict__ src,
                                                    float* __restrict__ xd,
                                                    short* __restrict__ xb) {
  int idx = blockIdx.x * 256 + threadIdx.x;
  int fi = idx << 2;
  int hi = (fi >> 19) & 1;
  int lo = (fi >> 18) & 1;
  int sj = (fi & ~(3 << 18)) | (lo << 19) | (hi << 18);
  float4 v = *(const float4*)&src[sj];
  *(float4*)&xd[fi] = v;
  uint2 uu; uu.x = pack2(v.x, v.y); uu.y = pack2(v.z, v.w);
  *(uint2*)&xb[fi] = uu;
}

__global__ __launch_bounds__(256) void swap_copy_out(const float* __restrict__ src,
                                                     float* __restrict__ dst) {
  int idx = blockIdx.x * 256 + threadIdx.x;
  int fi = idx << 2;
  int hi = (fi >> 19) & 1;
  int lo = (fi >> 18) & 1;
  int sj = (fi & ~(3 << 18)) | (lo << 19) | (hi << 18);
  *(float4*)&dst[fi] = *(const float4*)&src[sj];
}

// ---------- weight transpose + fp32->bf16: Wt[n][k].  160 blocks per layer.
// per-layer wbuf layout (shorts): qwt@0 kwt@65536 vwt@131072 owt@196608 w1t@262144 w2t@524288
__global__ __launch_bounds__(256) void wconv(
    const float* __restrict__ qw, const float* __restrict__ kw,
    const float* __restrict__ vw, const float* __restrict__ ow,
    const float* __restrict__ w1, const float* __restrict__ w2,
    short* __restrict__ wbuf, int layer0) {
  __shared__ float T[64][65];
  int blk = blockIdx.x;
  int layer = layer0 + blk / 160;
  int sub = blk % 160;
  const float* W; int Kd, Nd, k0, n0; size_t ooff;
  if (sub < 64) {
    int wsel = sub >> 4; int t = sub & 15;
    k0 = (t >> 2) * 64; n0 = (t & 3) * 64; Kd = 256; Nd = 256;
    W = (wsel == 0 ? qw : wsel == 1 ? kw : wsel == 2 ? vw : ow) + (size_t)layer * 65536;
    ooff = (size_t)wsel * 65536;
  } else if (sub < 128) {
    int t = sub - 64; k0 = (t >> 3) * 64; n0 = (t & 7) * 64;
    Kd = 512; Nd = 512; W = w1 + (size_t)layer * 262144; ooff = 262144;
  } else {
    int t = sub - 128; k0 = (t >> 2) * 64; n0 = (t & 3) * 64;
    Kd = 512; Nd = 256; W = w2 + (size_t)layer * 131072; ooff = 524288;
  }
  short* out = wbuf + (size_t)(layer - layer0) * 655360 + ooff;
  int t = threadIdx.x;
  int r = t >> 4, c4 = (t & 15) * 4;
#pragma unroll
  for (int rr = 0; rr < 4; ++rr) {
    float4 v = *(const float4*)&W[(size_t)(k0 + r + rr * 16) * Nd + n0 + c4];
    T[r + rr * 16][c4 + 0] = v.x; T[r + rr * 16][c4 + 1] = v.y;
    T[r + rr * 16][c4 + 2] = v.z; T[r + rr * 16][c4 + 3] = v.w;
  }
  __syncthreads();
  int n = t >> 2, kc = (t & 3) * 16;
  unsigned u[8];
#pragma unroll
  for (int j2 = 0; j2 < 8; ++j2)
    u[j2] = pack2(T[kc + 2 * j2][n], T[kc + 2 * j2 + 1][n]);
  short* op = &out[(size_t)(n0 + n) * Kd + k0 + kc];
  uint4 o1; o1.x = u[0]; o1.y = u[1]; o1.z = u[2]; o1.w = u[3];
  uint4 o2; o2.x = u[4]; o2.y = u[5]; o2.z = u[6]; o2.w = u[7];
  *(uint4*)&op[0] = o1;
  *(uint4*)&op[8] = o2;
}

// ---------- shared MFMA K-step: BM=64 BN=128, waves 2x2, wave-tile 32x64
__device__ __forceinline__ void mfma_tile_step(const short* As, const short* Bs,
                                               int wy, int wx, int quad, int l16,
                                               floatx4 acc[2][4]) {
#pragma unroll
  for (int kk = 0; kk < 2; ++kk) {
    bf16x8 a0 = *(const bf16x8*)&As[(wy * 32 + l16) * 64 + kk * 32 + quad * 8];
    bf16x8 a1 = *(const bf16x8*)&As[(wy * 32 + 16 + l16) * 64 + kk * 32 + quad * 8];
    bf16x8 b[4];
#pragma unroll
    for (int ni = 0; ni < 4; ++ni)
      b[ni] = *(const bf16x8*)&Bs[(wx * 64 + ni * 16 + l16) * 64 + kk * 32 + quad * 8];
#pragma unroll
    for (int ni = 0; ni < 4; ++ni) {
      acc[0][ni] = __builtin_amdgcn_mfma_f32_16x16x32_bf16(a0, b[ni], acc[0][ni], 0, 0, 0);
      acc[1][ni] = __builtin_amdgcn_mfma_f32_16x16x32_bf16(a1, b[ni], acc[1][ni], 0, 0, 0);
    }
  }
}

#define GEMM_IDS                                      \
  const int tid = threadIdx.x;                        \
  const int lane = tid & 63, w = tid >> 6;            \
  const int wy = w >> 1, wx = w & 1;                  \
  const int quad = lane >> 4, l16 = lane & 15;        \
  const int lr = lane >> 3, lc = (lane & 7) * 8;      \
  const floatx4 z4 = {0.f, 0.f, 0.f, 0.f};            \
  floatx4 acc[2][4] = {{z4, z4, z4, z4}, {z4, z4, z4, z4}};

// ---------- fused QKV GEMM: C[4096 x 768], grid (64, 6). v-seg writes V^T.
__global__ __launch_bounds__(256) void gemm_qkv(
    const short* __restrict__ xb, const short* __restrict__ wbufL,
    const float* __restrict__ qb_, const float* __restrict__ kb_,
    const float* __restrict__ vb_,
    short* __restrict__ q, short* __restrict__ kout, short* __restrict__ vT,
    int cross) {
  __shared__ short SM[4096 + 8192];
  short* As = SM; short* Bs = SM + 4096;
  const int rb = blockIdx.x * 64;
  const int cb = blockIdx.y * 128;
  const int seg = cb >> 8;          // 0 q, 1 k, 2 v
  const int cbl = cb & 255;
  int arb = rb;
  if (seg) arb = (rb & 2047) | ((((rb >> 11) ^ cross) & 1) << 11);
  const short* A = xb + (size_t)arb * 256;
  const short* Wt = wbufL + (size_t)seg * 65536 + (size_t)cbl * 256;
  const float* bias = (seg == 0 ? qb_ : seg == 1 ? kb_ : vb_) + cbl;
  GEMM_IDS;

  for (int k0 = 0; k0 < 256; k0 += 64) {
    __syncthreads();
    gl2lds16(&A[(size_t)(w * 8 + lr) * 256 + k0 + lc], &As[(w * 8) * 64]);
    gl2lds16(&A[(size_t)(32 + w * 8 + lr) * 256 + k0 + lc], &As[(32 + w * 8) * 64]);
#pragma unroll
    for (int i = 0; i < 4; ++i)
      gl2lds16(&Wt[(size_t)(i * 32 + w * 8 + lr) * 256 + k0 + lc],
               &Bs[(i * 32 + w * 8) * 64]);
    __syncthreads();
    mfma_tile_step(As, Bs, wy, wx, quad, l16, acc);
  }

  if (seg < 2) {
    short* C = (seg == 0 ? q : kout) + (size_t)rb * 256 + cbl;
#pragma unroll
    for (int mi = 0; mi < 2; ++mi)
#pragma unroll
      for (int ni = 0; ni < 4; ++ni) {
        int col = wx * 64 + ni * 16 + l16;
        float bc = bias[col];
#pragma unroll
        for (int reg = 0; reg < 4; ++reg) {
          int row = wy * 32 + mi * 16 + quad * 4 + reg;
          C[(size_t)row * 256 + col] = f2b(acc[mi][ni][reg] + bc);
        }
      }
  } else {
    // transpose into vT[z][d][key]
    __syncthreads();
    short* T = SM + w * 2560;       // 64 dims x 40 (pad)
    const int sb = rb >> 10;
    const int hh = (cbl >> 6) + wx;
    const int z = sb * 4 + hh;
#pragma unroll
    for (int mi = 0; mi < 2; ++mi)
#pragma unroll
      for (int ni = 0; ni < 4; ++ni) {
        int col = wx * 64 + ni * 16 + l16;
        float bc = bias[col];
#pragma unroll
        for (int reg = 0; reg < 4; ++reg)
          T[(ni * 16 + l16) * 40 + mi * 16 + quad * 4 + reg] =
              f2b(acc[mi][ni][reg] + bc);
      }
    short* dst = &vT[((size_t)z * 64 + lane) * 1024 + (rb & 1023) + wy * 32];
#pragma unroll
    for (int c = 0; c < 4; ++c)
      *(uint4*)&dst[c * 8] = *(const uint4*)&T[lane * 40 + c * 8];
  }
}

// ---------- flash attention: grid (qt=16, z=16), 4 waves, 16 queries/wave,
// double-buffered async staging, no split-K.
__global__ __launch_bounds__(256) void attn_mfma(
    const short* __restrict__ q, const short* __restrict__ k,
    const short* __restrict__ vT, const int* __restrict__ mask,
    short* __restrict__ attnb, int cross) {
  __shared__ short Ks[2][4096];
  __shared__ short Vs[2][4096];
  __shared__ short Pw[4][16 * 72];
  __shared__ float Ms[2][64];
  const int tid = threadIdx.x;
  const int lane = tid & 63, w = tid >> 6;
  const int quad = lane >> 4, l16 = lane & 15;
  const int lr = lane >> 3, lc = (lane & 7) * 8;
  const int qt = blockIdx.x;
  const int z = blockIdx.y;
  const int sb = z >> 2, h = z & 3;
  const int s = sb >> 1, b = sb & 1;
  const int rowbase = sb * 1024;
  const int* mp = mask + (b * 2 + (s ^ cross)) * 1024;

  const int qrow = qt * 64 + w * 16 + l16;
  bf16x8 qf[2];
#pragma unroll
  for (int kk = 0; kk < 2; ++kk)
    qf[kk] = *(const bf16x8*)&q[(size_t)(rowbase + qrow) * 256 + h * 64 + kk * 32 + quad * 8];

  const floatx4 z4 = {0.f, 0.f, 0.f, 0.f};
  floatx4 o4[4] = {z4, z4, z4, z4};
  float mrun[4] = {-1e30f, -1e30f, -1e30f, -1e30f};
  float lsum[4] = {0.f, 0.f, 0.f, 0.f};

#define STAGE(t, buf)                                                                   \
  {                                                                                     \
    int key0 = (t) * 64;                                                                \
    gl2lds16(&k[(size_t)(rowbase + key0 + w * 8 + lr) * 256 + h * 64 + lc],             \
             &Ks[buf][(w * 8) * 64]);                                                   \
    gl2lds16(&k[(size_t)(rowbase + key0 + 32 + w * 8 + lr) * 256 + h * 64 + lc],        \
             &Ks[buf][(32 + w * 8) * 64]);                                              \
    gl2lds16(&vT[((size_t)z * 64 + w * 8 + lr) * 1024 + key0 + lc],                     \
             &Vs[buf][(w * 8) * 64]);                                                   \
    gl2lds16(&vT[((size_t)z * 64 + 32 + w * 8 + lr) * 1024 + key0 + lc],                \
             &Vs[buf][(32 + w * 8) * 64]);                                              \
    if (tid < 64) Ms[buf][tid] = (mp[key0 + tid] == 0) ? -1.0e9f : 0.f;                 \
  }

  STAGE(0, 0);
  __syncthreads();
  for (int t = 0; t < 16; ++t) {
    int buf = t & 1;
    if (t < 15) STAGE(t + 1, buf ^ 1);

    floatx4 sA[4] = {z4, z4, z4, z4};
#pragma unroll
    for (int kk = 0; kk < 2; ++kk)
#pragma unroll
      for (int nt = 0; nt < 4; ++nt) {
        bf16x8 kf = *(const bf16x8*)&Ks[buf][(nt * 16 + l16) * 64 + kk * 32 + quad * 8];
        sA[nt] = __builtin_amdgcn_mfma_f32_16x16x32_bf16(qf[kk], kf, sA[nt], 0, 0, 0);
      }
    float scv[4][4];
#pragma unroll
    for (int nt = 0; nt < 4; ++nt) {
      float mk = Ms[buf][nt * 16 + l16];
#pragma unroll
      for (int reg = 0; reg < 4; ++reg) scv[nt][reg] = sA[nt][reg] * 0.125f + mk;
    }
    float rmx[4];
#pragma unroll
    for (int reg = 0; reg < 4; ++reg) {
      float m0 = fmaxf(fmaxf(scv[0][reg], scv[1][reg]), fmaxf(scv[2][reg], scv[3][reg]));
#pragma unroll
      for (int d = 1; d < 16; d <<= 1) m0 = fmaxf(m0, __shfl_xor(m0, d));
      rmx[reg] = m0;
    }
#pragma unroll
    for (int reg = 0; reg < 4; ++reg) {
      float mnew = fmaxf(mrun[reg], rmx[reg]);
      float corr = __expf(mrun[reg] - mnew);
      mrun[reg] = mnew;
      lsum[reg] *= corr;
#pragma unroll
      for (int dt = 0; dt < 4; ++dt) o4[dt][reg] *= corr;
      float ps = 0.f;
#pragma unroll
      for (int nt = 0; nt < 4; ++nt) {
        float e = __expf(scv[nt][reg] - mnew);
        ps += e;
        Pw[w][(quad * 4 + reg) * 72 + nt * 16 + l16] = f2b(e);
      }
      lsum[reg] += ps;
    }
#pragma unroll
    for (int kk = 0; kk < 2; ++kk) {
      bf16x8 pf = *(const bf16x8*)&Pw[w][l16 * 72 + kk * 32 + quad * 8];
#pragma unroll
      for (int dt = 0; dt < 4; ++dt) {
        bf16x8 vf = *(const bf16x8*)&Vs[buf][(dt * 16 + l16) * 64 + kk * 32 + quad * 8];
        o4[dt] = __builtin_amdgcn_mfma_f32_16x16x32_bf16(pf, vf, o4[dt], 0, 0, 0);
      }
    }
    __syncthreads();
  }
#pragma unroll
  for (int reg = 0; reg < 4; ++reg)
#pragma unroll
    for (int d = 1; d < 16; d <<= 1) lsum[reg] += __shfl_xor(lsum[reg], d);
#pragma unroll
  for (int reg = 0; reg < 4; ++reg) {
    float inv = 1.f / lsum[reg];
    int row = rowbase + qt * 64 + w * 16 + quad * 4 + reg;
#pragma unroll
    for (int dt = 0; dt < 4; ++dt)
      attnb[(size_t)row * 256 + h * 64 + dt * 16 + l16] = f2b(o4[dt][reg] * inv);
  }
}

// ---------- O-projection GEMM: grid (64, 2)
__global__ __launch_bounds__(256) void gemm_o(
    const short* __restrict__ attnb, const short* __restrict__ owt,
    const float* __restrict__ ob_, short* __restrict__ aob) {
  __shared__ short SM[4096 + 8192];
  short* As = SM; short* Bs = SM + 4096;
  const int rb = blockIdx.x * 64, cb = blockIdx.y * 128;
  const short* A = attnb + (size_t)rb * 256;
  const short* Wt = owt + (size_t)cb * 256;
  GEMM_IDS;
  for (int k0 = 0; k0 < 256; k0 += 64) {
    __syncthreads();
    gl2lds16(&A[(size_t)(w * 8 + lr) * 256 + k0 + lc], &As[(w * 8) * 64]);
    gl2lds16(&A[(size_t)(32 + w * 8 + lr) * 256 + k0 + lc], &As[(32 + w * 8) * 64]);
#pragma unroll
    for (int i = 0; i < 4; ++i)
      gl2lds16(&Wt[(size_t)(i * 32 + w * 8 + lr) * 256 + k0 + lc],
               &Bs[(i * 32 + w * 8) * 64]);
    __syncthreads();
    mfma_tile_step(As, Bs, wy, wx, quad, l16, acc);
  }
  short* C = aob + (size_t)rb * 256 + cb;
#pragma unroll
  for (int mi = 0; mi < 2; ++mi)
#pragma unroll
    for (int ni = 0; ni < 4; ++ni) {
      int col = wx * 64 + ni * 16 + l16;
      float bc = ob_[cb + col];
#pragma unroll
      for (int reg = 0; reg < 4; ++reg) {
        int row = wy * 32 + mi * 16 + quad * 4 + reg;
        C[(size_t)row * 256 + col] = f2b(acc[mi][ni][reg] + bc);
      }
    }
}

// ---------- W1 GEMM (concat [x|a]) + per-block BN column partials. grid (64, 4)
__global__ __launch_bounds__(256) void gemm_w1(
    const short* __restrict__ xb, const short* __restrict__ aob,
    const short* __restrict__ w1t, const float* __restrict__ b1_,
    float* __restrict__ hbuf, float* __restrict__ psum, float* __restrict__ psq) {
  __shared__ short SM[4096 + 8192];
  __shared__ float Ps[2][2][128];
  short* As = SM; short* Bs = SM + 4096;
  const int rb = blockIdx.x * 64, cb = blockIdx.y * 128;
  GEMM_IDS;
  for (int k0 = 0; k0 < 512; k0 += 64) {
    const short* Ap = (k0 < 256 ? xb : aob) + (size_t)rb * 256;
    int kb = k0 & 255;
    __syncthreads();
    gl2lds16(&Ap[(size_t)(w * 8 + lr) * 256 + kb + lc], &As[(w * 8) * 64]);
    gl2lds16(&Ap[(size_t)(32 + w * 8 + lr) * 256 + kb + lc], &As[(32 + w * 8) * 64]);
#pragma unroll
    for (int i = 0; i < 4; ++i)
      gl2lds16(&w1t[(size_t)(cb + i * 32 + w * 8 + lr) * 512 + k0 + lc],
               &Bs[(i * 32 + w * 8) * 64]);
    __syncthreads();
    mfma_tile_step(As, Bs, wy, wx, quad, l16, acc);
  }
  float colsum[4], colsq[4];
#pragma unroll
  for (int ni = 0; ni < 4; ++ni) { colsum[ni] = 0.f; colsq[ni] = 0.f; }
#pragma unroll
  for (int mi = 0; mi < 2; ++mi)
#pragma unroll
    for (int ni = 0; ni < 4; ++ni) {
      int col = wx * 64 + ni * 16 + l16;
      float bc = b1_[cb + col];
#pragma unroll
      for (int reg = 0; reg < 4; ++reg) {
        int row = rb + wy * 32 + mi * 16 + quad * 4 + reg;
        float val = acc[mi][ni][reg] + bc;
        hbuf[(size_t)row * 512 + cb + col] = val;
        colsum[ni] += val; colsq[ni] += val * val;
      }
    }
#pragma unroll
  for (int ni = 0; ni < 4; ++ni)
#pragma unroll
    for (int d = 16; d < 64; d <<= 1) {
      colsum[ni] += __shfl_xor(colsum[ni], d);
      colsq[ni]  += __shfl_xor(colsq[ni], d);
    }
  if (quad == 0) {
#pragma unroll
    for (int ni = 0; ni < 4; ++ni) {
      Ps[wy][0][wx * 64 + ni * 16 + l16] = colsum[ni];
      Ps[wy][1][wx * 64 + ni * 16 + l16] = colsq[ni];
    }
  }
  __syncthreads();
  if (tid < 128) {
    psum[(size_t)(cb + tid) * 64 + blockIdx.x] = Ps[0][0][tid] + Ps[1][0][tid];
    psq [(size_t)(cb + tid) * 64 + blockIdx.x] = Ps[0][1][tid] + Ps[1][1][tid];
  }
}

// ---------- W2 GEMM: BN finalize prologue + BN/ReLU fused A-staging + residual.
// grid (64, 2)
__global__ __launch_bounds__(256) void gemm_w2(
    const float* __restrict__ hbuf, const short* __restrict__ w2t,
    const float* __restrict__ b2_, const float* __restrict__ psum,
    const float* __restrict__ psq, const float* __restrict__ g,
    const float* __restrict__ be, float* __restrict__ xd, short* __restrict__ xb) {
  __shared__ short SM[4096 + 8192];
  __shared__ float s_scale[512], s_shift[512];
  short* As = SM; short* Bs = SM + 4096;
  const int rb = blockIdx.x * 64, cb = blockIdx.y * 128;
  const int s = blockIdx.x >> 5;
  GEMM_IDS;
#pragma unroll
  for (int cc = 0; cc < 2; ++cc) {
    int c = tid + cc * 256;
    float sum = 0.f, sq = 0.f;
#pragma unroll
    for (int g4 = 0; g4 < 8; ++g4) {
      float4 a  = *(const float4*)&psum[(size_t)c * 64 + s * 32 + g4 * 4];
      float4 bq = *(const float4*)&psq [(size_t)c * 64 + s * 32 + g4 * 4];
      sum += a.x + a.y + a.z + a.w;
      sq  += bq.x + bq.y + bq.z + bq.w;
    }
    float mean = sum * (1.f / 2048.f);
    float var = sq * (1.f / 2048.f) - mean * mean;
    float rstd = rsqrtf(var + 1e-5f);
    float gs = g[c] * rstd;
    s_scale[c] = gs;
    s_shift[c] = be[c] - mean * gs;
  }
  for (int k0 = 0; k0 < 512; k0 += 64) {
    __syncthreads();
#pragma unroll
    for (int half = 0; half < 2; ++half) {
      int ar = (tid >> 3) + half * 32;
      int akc = (tid & 7) * 8;
      float4 h0 = *(const float4*)&hbuf[(size_t)(rb + ar) * 512 + k0 + akc];
      float4 h1 = *(const float4*)&hbuf[(size_t)(rb + ar) * 512 + k0 + akc + 4];
      float4 sc0 = *(const float4*)&s_scale[k0 + akc];
      float4 sc1 = *(const float4*)&s_scale[k0 + akc + 4];
      float4 sh0 = *(const float4*)&s_shift[k0 + akc];
      float4 sh1 = *(const float4*)&s_shift[k0 + akc + 4];
      float r0 = fmaxf(h0.x * sc0.x + sh0.x, 0.f);
      float r1 = fmaxf(h0.y * sc0.y + sh0.y, 0.f);
      float r2 = fmaxf(h0.z * sc0.z + sh0.z, 0.f);
      float r3 = fmaxf(h0.w * sc0.w + sh0.w, 0.f);
      float r4 = fmaxf(h1.x * sc1.x + sh1.x, 0.f);
      float r5 = fmaxf(h1.y * sc1.y + sh1.y, 0.f);
      float r6 = fmaxf(h1.z * sc1.z + sh1.z, 0.f);
      float r7 = fmaxf(h1.w * sc1.w + sh1.w, 0.f);
      uint4 pk;
      pk.x = pack2(r0, r1); pk.y = pack2(r2, r3);
      pk.z = pack2(r4, r5); pk.w = pack2(r6, r7);
      *(uint4*)&As[ar * 64 + akc] = pk;
    }
#pragma unroll
    for (int i = 0; i < 4; ++i)
      gl2lds16(&w2t[(size_t)(cb + i * 32 + w * 8 + lr) * 512 + k0 + lc],
               &Bs[(i * 32 + w * 8) * 64]);
    __syncthreads();
    mfma_tile_step(As, Bs, wy, wx, quad, l16, acc);
  }
#pragma unroll
  for (int mi = 0; mi < 2; ++mi)
#pragma unroll
    for (int ni = 0; ni < 4; ++ni) {
      int col = cb + wx * 64 + ni * 16 + l16;
      float bc = b2_[col];
#pragma unroll
      for (int reg = 0; reg < 4; ++reg) {
        int row = rb + wy * 32 + mi * 16 + quad * 4 + reg;
        float r = xd[(size_t)row * 256 + col] + acc[mi][ni][reg] + bc;
        xd[(size_t)row * 256 + col] = r;
        xb[(size_t)row * 256 + col] = f2b(r);
      }
    }
}

extern "C" void kernel_launch(void* const* d_in, const int* in_sizes, int n_in,
                              void* d_out, int out_size, void* d_ws, size_t ws_size,
                              hipStream_t stream) {
  (void)in_sizes; (void)n_in; (void)out_size;
  const float* desc = (const float*)d_in[0];
  const int*   mask = (const int*)d_in[1];
  const float* qw = (const float*)d_in[2];
  const float* qb = (const float*)d_in[3];
  const float* kw = (const float*)d_in[4];
  const float* kb = (const float*)d_in[5];
  const float* vw = (const float*)d_in[6];
  const float* vb = (const float*)d_in[7];
  const float* ow = (const float*)d_in[8];
  const float* ob = (const float*)d_in[9];
  const float* w1 = (const float*)d_in[10];
  const float* b1 = (const float*)d_in[11];
  const float* bn_g = (const float*)d_in[12];
  const float* bn_b = (const float*)d_in[13];
  const float* w2 = (const float*)d_in[14];
  const float* b2 = (const float*)d_in[15];
  float* out = (float*)d_out;

  char* base = (char*)d_ws;
  float* xd    = (float*)(base);                  // [0,4) MB
  float* hbuf  = (float*)(base + (4u << 20));     // [4,12) MB fp32 4096x512
  short* xb    = (short*)(base + (12u << 20));    // 2 MB
  short* qb16  = (short*)(base + (14u << 20));
  short* kb16  = (short*)(base + (16u << 20));
  short* vTb   = (short*)(base + (18u << 20));    // V^T per layer, 2 MB
  short* attnb = (short*)(base + (20u << 20));
  short* aob   = (short*)(base + (22u << 20));
  float* psum  = (float*)(base + (24u << 20));    // [512][64]
  float* psq   = psum + 32768;
  short* wbuf  = (short*)(base + (25u << 20));

  const int hoist = (ws_size >= ((size_t)50 << 20)) ? 1 : 0;

  swap_copy_in<<<1024, 256, 0, stream>>>(desc, xd, xb);
  if (hoist)
    wconv<<<160 * 18, 256, 0, stream>>>(qw, kw, vw, ow, w1, w2, wbuf, 0);

  for (int i = 0; i < 18; ++i) {
    int cross = i & 1;
    short* wb = hoist ? wbuf + (size_t)i * 655360 : wbuf;
    if (!hoist)
      wconv<<<160, 256, 0, stream>>>(qw, kw, vw, ow, w1, w2, wbuf, i);

    gemm_qkv<<<dim3(64, 6), 256, 0, stream>>>(
        xb, wb, qb + (size_t)i * 256, kb + (size_t)i * 256, vb + (size_t)i * 256,
        qb16, kb16, vTb, cross);
    attn_mfma<<<dim3(16, 16), 256, 0, stream>>>(qb16, kb16, vTb, mask, attnb, cross);
    gemm_o<<<dim3(64, 2), 256, 0, stream>>>(attnb, wb + 196608,
                                            ob + (size_t)i * 256, aob);
    gemm_w1<<<dim3(64, 4), 256, 0, stream>>>(xb, aob, wb + 262144,
                                             b1 + (size_t)i * 512, hbuf, psum, psq);
    gemm_w2<<<dim3(64, 2), 256, 0, stream>>>(hbuf, wb + 524288,
                                             b2 + (size_t)i * 256, psum, psq,
                                             bn_g + (size_t)i * 512,
                                             bn_b + (size_t)i * 512, xd, xb);
  }

  swap_copy_out<<<1024, 256, 0, stream>>>(xd, out);
}

// Round 5
// 1303.306 us; speedup vs baseline: 9.3966x; 1.1597x over previous
//
#include <hip/hip_runtime.h>

// B=2, streams=2, N=1024, D=256, H=4, DH=64, L=18
// Row layout: r = s*2048 + b*1024 + n  (M=4096 rows)
// bf16 MFMA 16x16x32: A-frag lane=A[m=lane&15][k=quad*8+j]; B-frag B[k=quad*8+j][n=lane&15]
// C/D: col=lane&15, row=quad*4+reg
// LDS XOR swizzle: 16B chunk c of row r is stored at slot (c ^ (r&7)).
// Staging (global_load_lds, 16B/lane): lane writes slot (lane&7) of row (lane>>3),
// so its global source chunk is ((lane&7) ^ ((lane>>3)&7)).

typedef __attribute__((ext_vector_type(8))) short bf16x8;
typedef __attribute__((ext_vector_type(4))) short bf16x4;
typedef __attribute__((ext_vector_type(4))) float floatx4;

__device__ __forceinline__ short f2b(float f) {   // fp32 -> bf16 RNE
  unsigned u = __builtin_bit_cast(unsigned, f);
  unsigned r = (u + 0x7FFFu + ((u >> 16) & 1u)) >> 16;
  return (short)r;
}
__device__ __forceinline__ unsigned pack2(float a, float b) {
  return (unsigned)(unsigned short)f2b(a) | ((unsigned)(unsigned short)f2b(b) << 16);
}

__device__ __forceinline__ void gl2lds16(const void* g, void* l) {
  __builtin_amdgcn_global_load_lds(
      (const __attribute__((address_space(1))) unsigned*)g,
      (__attribute__((address_space(3))) unsigned*)l, 16, 0, 0);
}

__device__ __forceinline__ floatx4 mfma16_bf16(bf16x4 a, bf16x4 b, floatx4 c) {
#if __has_builtin(__builtin_amdgcn_mfma_f32_16x16x16_bf16)
  return __builtin_amdgcn_mfma_f32_16x16x16_bf16(a, b, c, 0, 0, 0);
#elif __has_builtin(__builtin_amdgcn_mfma_f32_16x16x16bf16_1k)
  return __builtin_amdgcn_mfma_f32_16x16x16bf16_1k(a, b, c, 0, 0, 0);
#else
  asm volatile("v_mfma_f32_16x16x16_bf16 %0, %1, %2, %0" : "+v"(c) : "v"(a), "v"(b));
  return c;
#endif
}

// ---------- input copy with (s,b) swap; writes fp32 residual + bf16 copy
__global__ __launch_bounds__(256) void swap_copy_in(const float* __restrict__ src,
                                                    float* __restrict__ xd,
                                                    short* __restrict__ xb) {
  int idx = blockIdx.x * 256 + threadIdx.x;
  int fi = idx << 2;
  int hi = (fi >> 19) & 1;
  int lo = (fi >> 18) & 1;
  int sj = (fi & ~(3 << 18)) | (lo << 19) | (hi << 18);
  float4 v = *(const float4*)&src[sj];
  *(float4*)&xd[fi] = v;
  uint2 uu; uu.x = pack2(v.x, v.y); uu.y = pack2(v.z, v.w);
  *(uint2*)&xb[fi] = uu;
}

__global__ __launch_bounds__(256) void swap_copy_out(const float* __restrict__ src,
                                                     float* __restrict__ dst) {
  int idx = blockIdx.x * 256 + threadIdx.x;
  int fi = idx << 2;
  int hi = (fi >> 19) & 1;
  int lo = (fi >> 18) & 1;
  int sj = (fi & ~(3 << 18)) | (lo << 19) | (hi << 18);
  *(float4*)&dst[fi] = *(const float4*)&src[sj];
}

// ---------- weight transpose + convert: Wt[n][k]. 112 blocks/layer.
// per-layer wbuf (shorts): qwt@0 kwt@65536 vwt@131072 w1t@262144(512x512) w2t@524288
__global__ __launch_bounds__(256) void wconv(
    const float* __restrict__ qw, const float* __restrict__ kw,
    const float* __restrict__ vw, const float* __restrict__ w1,
    const float* __restrict__ w2, short* __restrict__ wbuf, int layer0) {
  __shared__ float T[64][65];
  int blk = blockIdx.x;
  int layer = layer0 + blk / 112;
  int sub = blk % 112;
  const float* W; int Kd, Nd, k0, n0; size_t ooff;
  if (sub < 48) {
    int wsel = sub >> 4; int t = sub & 15;
    k0 = (t >> 2) * 64; n0 = (t & 3) * 64; Kd = 256; Nd = 256;
    W = (wsel == 0 ? qw : wsel == 1 ? kw : vw) + (size_t)layer * 65536;
    ooff = (size_t)wsel * 65536;
  } else if (sub < 80) {
    int t = sub - 48; k0 = (t >> 3) * 64; n0 = (t & 7) * 64;   // k0<256 (top half)
    Kd = 512; Nd = 512; W = w1 + (size_t)layer * 262144; ooff = 262144;
  } else {
    int t = sub - 80; k0 = (t >> 2) * 64; n0 = (t & 3) * 64;
    Kd = 512; Nd = 256; W = w2 + (size_t)layer * 131072; ooff = 524288;
  }
  short* out = wbuf + (size_t)(layer - layer0) * 655360 + ooff;
  int t = threadIdx.x;
  int r = t >> 4, c4 = (t & 15) * 4;
#pragma unroll
  for (int rr = 0; rr < 4; ++rr) {
    float4 v = *(const float4*)&W[(size_t)(k0 + r + rr * 16) * Nd + n0 + c4];
    T[r + rr * 16][c4 + 0] = v.x; T[r + rr * 16][c4 + 1] = v.y;
    T[r + rr * 16][c4 + 2] = v.z; T[r + rr * 16][c4 + 3] = v.w;
  }
  __syncthreads();
  int n = t >> 2, kc = (t & 3) * 16;
  unsigned u[8];
#pragma unroll
  for (int j2 = 0; j2 < 8; ++j2)
    u[j2] = pack2(T[kc + 2 * j2][n], T[kc + 2 * j2 + 1][n]);
  short* op = &out[(size_t)(n0 + n) * Kd + k0 + kc];
  uint4 o1; o1.x = u[0]; o1.y = u[1]; o1.z = u[2]; o1.w = u[3];
  uint4 o2; o2.x = u[4]; o2.y = u[5]; o2.z = u[6]; o2.w = u[7];
  *(uint4*)&op[0] = o1;
  *(uint4*)&op[8] = o2;
}

// ---------- fused weight: F = ow @ w1[256:512]; write F^T into w1t[n][256+k'].
// 32 blocks/layer: t = n-tile(8) x k'-tile(4). fp32 SIMT 64x64 tile.
__global__ __launch_bounds__(256) void wfuse(
    const float* __restrict__ ow, const float* __restrict__ w1,
    short* __restrict__ wbuf, int layer0) {
  __shared__ float As[16][64];
  __shared__ float Bs[16][65];
  int blk = blockIdx.x;
  int layer = layer0 + blk / 32;
  int sub = blk % 32;
  int n0 = (sub & 7) * 64, kp0 = (sub >> 3) * 64;
  const float* A = ow + (size_t)layer * 65536 + (size_t)kp0 * 256;     // [kp][i]
  const float* B = w1 + (size_t)layer * 262144 + 256 * 512 + n0;      // [i][n]
  const int tid = threadIdx.x;
  const int tx = tid & 15, ty = tid >> 4;
  const int a_r = tid >> 2, a_k = (tid & 3) << 2;
  const int b_k = tid >> 4, b_n = (tid & 15) << 2;
  float acc[4][4];
#pragma unroll
  for (int i = 0; i < 4; ++i)
#pragma unroll
    for (int j = 0; j < 4; ++j) acc[i][j] = 0.f;
  for (int i0 = 0; i0 < 256; i0 += 16) {
    float4 av = *(const float4*)&A[(size_t)a_r * 256 + i0 + a_k];
    float4 bv = *(const float4*)&B[(size_t)(i0 + b_k) * 512 + b_n];
    __syncthreads();
    As[a_k + 0][a_r] = av.x; As[a_k + 1][a_r] = av.y;
    As[a_k + 2][a_r] = av.z; As[a_k + 3][a_r] = av.w;
    *(float4*)&Bs[b_k][b_n] = bv;
    __syncthreads();
#pragma unroll
    for (int kk = 0; kk < 16; ++kk) {
      float4 a4 = *(const float4*)&As[kk][ty << 2];
      float4 b4 = *(const float4*)&Bs[kk][tx << 2];
      float aa[4] = {a4.x, a4.y, a4.z, a4.w};
      float bb[4] = {b4.x, b4.y, b4.z, b4.w};
#pragma unroll
      for (int i = 0; i < 4; ++i)
#pragma unroll
        for (int j = 0; j < 4; ++j) acc[i][j] += aa[i] * bb[j];
    }
  }
  short* w1t = wbuf + (size_t)(layer - layer0) * 655360 + 262144;
#pragma unroll
  for (int i = 0; i < 4; ++i)
#pragma unroll
    for (int j = 0; j < 4; ++j)
      w1t[(size_t)(n0 + tx * 4 + j) * 512 + 256 + kp0 + ty * 4 + i] = f2b(acc[i][j]);
}

// ---------- fused bias: beff[l][n] = b1[l][n] + sum_i ob[l][i]*w1[l][256+i][n]
__global__ __launch_bounds__(256) void bfuse(
    const float* __restrict__ ob, const float* __restrict__ w1,
    const float* __restrict__ b1, float* __restrict__ beff, int layer0) {
  int layer = layer0 + blockIdx.x;
  const float* obL = ob + (size_t)layer * 256;
  const float* w1L = w1 + (size_t)layer * 262144 + 256 * 512;
  float* be = beff + (size_t)blockIdx.x * 512;
#pragma unroll
  for (int cc = 0; cc < 2; ++cc) {
    int n = threadIdx.x + cc * 256;
    float s = b1[(size_t)layer * 512 + n];
    for (int i = 0; i < 256; ++i) s += obL[i] * w1L[(size_t)i * 512 + n];
    be[n] = s;
  }
}

#define GEMM_IDS                                        \
  const int tid = threadIdx.x;                          \
  const int lane = tid & 63, w = tid >> 6;              \
  const int wy = w >> 1, wx = w & 1;                    \
  const int quad = lane >> 4, l16 = lane & 15;          \
  const int lr = lane >> 3;                             \
  const int lcs = (((lane & 7) ^ lr) & 7) * 8;          \
  const floatx4 z4 = {0.f, 0.f, 0.f, 0.f};              \
  floatx4 acc[2][4] = {{z4, z4, z4, z4}, {z4, z4, z4, z4}};

// swizzled MFMA K-step (BM=64, BN=128, wave-tile 32x64)
__device__ __forceinline__ void mfma_step_sw(const short* As, const short* Bs,
                                             int wy, int wx, int quad, int l16,
                                             floatx4 acc[2][4]) {
#pragma unroll
  for (int kk = 0; kk < 2; ++kk) {
    const int sw = (((kk * 4 + quad) ^ (l16 & 7)) * 8);
    bf16x8 a0 = *(const bf16x8*)&As[(wy * 32 + l16) * 64 + sw];
    bf16x8 a1 = *(const bf16x8*)&As[(wy * 32 + 16 + l16) * 64 + sw];
    bf16x8 b[4];
#pragma unroll
    for (int ni = 0; ni < 4; ++ni)
      b[ni] = *(const bf16x8*)&Bs[(wx * 64 + ni * 16 + l16) * 64 + sw];
#pragma unroll
    for (int ni = 0; ni < 4; ++ni) {
      acc[0][ni] = __builtin_amdgcn_mfma_f32_16x16x32_bf16(a0, b[ni], acc[0][ni], 0, 0, 0);
      acc[1][ni] = __builtin_amdgcn_mfma_f32_16x16x32_bf16(a1, b[ni], acc[1][ni], 0, 0, 0);
    }
  }
}

// ---------- fused QKV GEMM: grid (64, 6); v-seg writes V^T
__global__ __launch_bounds__(256) void gemm_qkv(
    const short* __restrict__ xb, const short* __restrict__ wbufL,
    const float* __restrict__ qb_, const float* __restrict__ kb_,
    const float* __restrict__ vb_,
    short* __restrict__ q, short* __restrict__ kout, short* __restrict__ vT,
    int cross) {
  __shared__ short SM[2 * 4096 + 2 * 8192];
  short* As = SM;            // [2][4096]
  short* Bs = SM + 8192;     // [2][8192]
  const int rb = blockIdx.x * 64;
  const int cb = blockIdx.y * 128;
  const int seg = cb >> 8;
  const int cbl = cb & 255;
  int arb = rb;
  if (seg) arb = (rb & 2047) | ((((rb >> 11) ^ cross) & 1) << 11);
  const short* A = xb + (size_t)arb * 256;
  const short* Wt = wbufL + (size_t)seg * 65536 + (size_t)cbl * 256;
  const float* bias = (seg == 0 ? qb_ : seg == 1 ? kb_ : vb_) + cbl;
  GEMM_IDS;

#define QKV_STAGE(s, buf)                                                          \
  {                                                                                \
    int k0 = (s) * 64;                                                             \
    gl2lds16(&A[(size_t)(w * 8 + lr) * 256 + k0 + lcs], &As[(buf) * 4096 + (w * 8) * 64]); \
    gl2lds16(&A[(size_t)(32 + w * 8 + lr) * 256 + k0 + lcs], &As[(buf) * 4096 + (32 + w * 8) * 64]); \
    _Pragma("unroll") for (int i = 0; i < 4; ++i)                                  \
      gl2lds16(&Wt[(size_t)(i * 32 + w * 8 + lr) * 256 + k0 + lcs],                \
               &Bs[(buf) * 8192 + (i * 32 + w * 8) * 64]);                         \
  }

  QKV_STAGE(0, 0);
  __syncthreads();
  for (int s = 0; s < 4; ++s) {
    int buf = s & 1;
    if (s < 3) QKV_STAGE(s + 1, buf ^ 1);
    mfma_step_sw(&As[buf * 4096], &Bs[buf * 8192], wy, wx, quad, l16, acc);
    __syncthreads();
  }

  if (seg < 2) {
    short* C = (seg == 0 ? q : kout) + (size_t)rb * 256 + cbl;
#pragma unroll
    for (int mi = 0; mi < 2; ++mi)
#pragma unroll
      for (int ni = 0; ni < 4; ++ni) {
        int col = wx * 64 + ni * 16 + l16;
        float bc = bias[col];
#pragma unroll
        for (int reg = 0; reg < 4; ++reg) {
          int row = wy * 32 + mi * 16 + quad * 4 + reg;
          C[(size_t)row * 256 + col] = f2b(acc[mi][ni][reg] + bc);
        }
      }
  } else {
    short* T = SM + w * 2560;       // 64 dims x 40 (pad)
    const int sb = rb >> 10;
    const int hh = (cbl >> 6) + wx;
    const int z = sb * 4 + hh;
#pragma unroll
    for (int mi = 0; mi < 2; ++mi)
#pragma unroll
      for (int ni = 0; ni < 4; ++ni) {
        int col = wx * 64 + ni * 16 + l16;
        float bc = bias[col];
#pragma unroll
        for (int reg = 0; reg < 4; ++reg)
          T[(ni * 16 + l16) * 40 + mi * 16 + quad * 4 + reg] =
              f2b(acc[mi][ni][reg] + bc);
      }
    short* dst = &vT[((size_t)z * 64 + lane) * 1024 + (rb & 1023) + wy * 32];
#pragma unroll
    for (int c = 0; c < 4; ++c)
      *(uint4*)&dst[c * 8] = *(const uint4*)&T[lane * 40 + c * 8];
  }
}

// ---------- flash attention, S^T/O^T form. grid (qt=16, z=16), 4 waves.
// S^T = K@Q^T (C: row=key, col=query) -> softmax per column (per-lane scalar state)
// -> P^T already in 16x16x16 B-frag layout -> O^T = V^T @ P^T from registers.
__global__ __launch_bounds__(256) void attn_mfma(
    const short* __restrict__ q, const short* __restrict__ k,
    const short* __restrict__ vT, const int* __restrict__ mask,
    short* __restrict__ attnb, int cross) {
  __shared__ short Ks[2][4096];
  __shared__ short Vs[2][4096];
  __shared__ float Ms[2][64];
  const int tid = threadIdx.x;
  const int lane = tid & 63, w = tid >> 6;
  const int quad = lane >> 4, l16 = lane & 15;
  const int lr = lane >> 3;
  const int lcs = (((lane & 7) ^ lr) & 7) * 8;
  const int qt = blockIdx.x;
  const int z = blockIdx.y;
  const int sb = z >> 2, h = z & 3;
  const int s = sb >> 1, b = sb & 1;
  const int rowbase = sb * 1024;
  const int* mp = mask + (b * 2 + (s ^ cross)) * 1024;

  const int qrow = qt * 64 + w * 16 + l16;      // this lane's query
  bf16x8 qf[2];
#pragma unroll
  for (int kk = 0; kk < 2; ++kk)
    qf[kk] = *(const bf16x8*)&q[(size_t)(rowbase + qrow) * 256 + h * 64 + kk * 32 + quad * 8];

  const floatx4 z4 = {0.f, 0.f, 0.f, 0.f};
  floatx4 o4[4] = {z4, z4, z4, z4};             // O^T: dim=dt*16+quad*4+reg, query=l16
  float mrun = -1e30f, lsum = 0.f;              // per-query scalar state (lsum = lane partial)

#define ATT_STAGE(t, buf)                                                               \
  {                                                                                     \
    int key0 = (t) * 64;                                                                \
    gl2lds16(&k[(size_t)(rowbase + key0 + w * 8 + lr) * 256 + h * 64 + lcs],            \
             &Ks[buf][(w * 8) * 64]);                                                   \
    gl2lds16(&k[(size_t)(rowbase + key0 + 32 + w * 8 + lr) * 256 + h * 64 + lcs],       \
             &Ks[buf][(32 + w * 8) * 64]);                                              \
    gl2lds16(&vT[((size_t)z * 64 + w * 8 + lr) * 1024 + key0 + lcs],                    \
             &Vs[buf][(w * 8) * 64]);                                                   \
    gl2lds16(&vT[((size_t)z * 64 + 32 + w * 8 + lr) * 1024 + key0 + lcs],               \
             &Vs[buf][(32 + w * 8) * 64]);                                              \
    if (tid < 64) Ms[buf][tid] = (mp[key0 + tid] == 0) ? -1.0e9f : 0.f;                 \
  }

  ATT_STAGE(0, 0);
  __syncthreads();
  for (int t = 0; t < 16; ++t) {
    int buf = t & 1;
    if (t < 15) ATT_STAGE(t + 1, buf ^ 1);

    // S^T tiles: A=K-frag (m=key), B=Q-frag (n=query)
    floatx4 sA[4] = {z4, z4, z4, z4};
#pragma unroll
    for (int kk = 0; kk < 2; ++kk) {
      const int sw = (((kk * 4 + quad) ^ (l16 & 7)) * 8);
#pragma unroll
      for (int mt = 0; mt < 4; ++mt) {
        bf16x8 kf = *(const bf16x8*)&Ks[buf][(mt * 16 + l16) * 64 + sw];
        sA[mt] = __builtin_amdgcn_mfma_f32_16x16x32_bf16(kf, qf[kk], sA[mt], 0, 0, 0);
      }
    }
    float scv[4][4];
    float tmax = -1e30f;
#pragma unroll
    for (int mt = 0; mt < 4; ++mt) {
      float4 mk = *(const float4*)&Ms[buf][mt * 16 + quad * 4];
      scv[mt][0] = sA[mt][0] * 0.125f + mk.x;
      scv[mt][1] = sA[mt][1] * 0.125f + mk.y;
      scv[mt][2] = sA[mt][2] * 0.125f + mk.z;
      scv[mt][3] = sA[mt][3] * 0.125f + mk.w;
#pragma unroll
      for (int reg = 0; reg < 4; ++reg) tmax = fmaxf(tmax, scv[mt][reg]);
    }
    tmax = fmaxf(tmax, __shfl_xor(tmax, 16));
    tmax = fmaxf(tmax, __shfl_xor(tmax, 32));
    float mnew = fmaxf(mrun, tmax);
    float corr = __expf(mrun - mnew);
    mrun = mnew;
    lsum *= corr;
#pragma unroll
    for (int dt = 0; dt < 4; ++dt)
#pragma unroll
      for (int reg = 0; reg < 4; ++reg) o4[dt][reg] *= corr;

    bf16x4 pb[4];
#pragma unroll
    for (int mt = 0; mt < 4; ++mt) {
      float e0 = __expf(scv[mt][0] - mnew);
      float e1 = __expf(scv[mt][1] - mnew);
      float e2 = __expf(scv[mt][2] - mnew);
      float e3 = __expf(scv[mt][3] - mnew);
      lsum += (e0 + e1) + (e2 + e3);
      union { bf16x4 v; uint2 u; } pu;
      pu.u.x = pack2(e0, e1); pu.u.y = pack2(e2, e3);
      pb[mt] = pu.v;
    }
    // O^T += V^T @ P^T  (P^T straight from registers)
#pragma unroll
    for (int mt = 0; mt < 4; ++mt) {
      const int c2 = mt * 2 + (quad >> 1);
      const int sub = (quad & 1) * 4;
#pragma unroll
      for (int dt = 0; dt < 4; ++dt) {
        bf16x4 vf = *(const bf16x4*)&Vs[buf][(dt * 16 + l16) * 64 +
                                             ((c2 ^ (l16 & 7)) * 8) + sub];
        o4[dt] = mfma16_bf16(vf, pb[mt], o4[dt]);
      }
    }
    __syncthreads();
  }
  lsum += __shfl_xor(lsum, 16);
  lsum += __shfl_xor(lsum, 32);
  float inv = 1.f / lsum;
  short* op = &attnb[(size_t)(rowbase + qrow) * 256 + h * 64 + quad * 4];
#pragma unroll
  for (int dt = 0; dt < 4; ++dt) {
    uint2 uu;
    uu.x = pack2(o4[dt][0] * inv, o4[dt][1] * inv);
    uu.y = pack2(o4[dt][2] * inv, o4[dt][3] * inv);
    *(uint2*)&op[dt * 16] = uu;
  }
}

// ---------- W1 GEMM (concat [x | attn], ow pre-fused) + BN column partials. grid (64,4)
__global__ __launch_bounds__(256) void gemm_w1(
    const short* __restrict__ xb, const short* __restrict__ attnb,
    const short* __restrict__ w1t, const float* __restrict__ beff,
    float* __restrict__ hbuf, float* __restrict__ psum, float* __restrict__ psq) {
  __shared__ short SM[2 * 4096 + 2 * 8192];
  __shared__ float Ps[2][2][128];
  short* As = SM;
  short* Bs = SM + 8192;
  const int rb = blockIdx.x * 64, cb = blockIdx.y * 128;
  GEMM_IDS;

#define W1_STAGE(s, buf)                                                            \
  {                                                                                 \
    int k0 = (s) * 64;                                                              \
    const short* Ap = ((s) < 4 ? xb : attnb) + (size_t)rb * 256;                    \
    int kb = k0 & 255;                                                              \
    gl2lds16(&Ap[(size_t)(w * 8 + lr) * 256 + kb + lcs], &As[(buf) * 4096 + (w * 8) * 64]); \
    gl2lds16(&Ap[(size_t)(32 + w * 8 + lr) * 256 + kb + lcs], &As[(buf) * 4096 + (32 + w * 8) * 64]); \
    _Pragma("unroll") for (int i = 0; i < 4; ++i)                                   \
      gl2lds16(&w1t[(size_t)(cb + i * 32 + w * 8 + lr) * 512 + k0 + lcs],           \
               &Bs[(buf) * 8192 + (i * 32 + w * 8) * 64]);                          \
  }

  W1_STAGE(0, 0);
  __syncthreads();
  for (int s = 0; s < 8; ++s) {
    int buf = s & 1;
    if (s < 7) W1_STAGE(s + 1, buf ^ 1);
    mfma_step_sw(&As[buf * 4096], &Bs[buf * 8192], wy, wx, quad, l16, acc);
    __syncthreads();
  }
  float colsum[4], colsq[4];
#pragma unroll
  for (int ni = 0; ni < 4; ++ni) { colsum[ni] = 0.f; colsq[ni] = 0.f; }
#pragma unroll
  for (int mi = 0; mi < 2; ++mi)
#pragma unroll
    for (int ni = 0; ni < 4; ++ni) {
      int col = wx * 64 + ni * 16 + l16;
      float bc = beff[cb + col];
#pragma unroll
      for (int reg = 0; reg < 4; ++reg) {
        int row = rb + wy * 32 + mi * 16 + quad * 4 + reg;
        float val = acc[mi][ni][reg] + bc;
        hbuf[(size_t)row * 512 + cb + col] = val;
        colsum[ni] += val; colsq[ni] += val * val;
      }
    }
#pragma unroll
  for (int ni = 0; ni < 4; ++ni)
#pragma unroll
    for (int d = 16; d < 64; d <<= 1) {
      colsum[ni] += __shfl_xor(colsum[ni], d);
      colsq[ni]  += __shfl_xor(colsq[ni], d);
    }
  if (quad == 0) {
#pragma unroll
    for (int ni = 0; ni < 4; ++ni) {
      Ps[wy][0][wx * 64 + ni * 16 + l16] = colsum[ni];
      Ps[wy][1][wx * 64 + ni * 16 + l16] = colsq[ni];
    }
  }
  __syncthreads();
  if (tid < 128) {
    psum[(size_t)(cb + tid) * 64 + blockIdx.x] = Ps[0][0][tid] + Ps[1][0][tid];
    psq [(size_t)(cb + tid) * 64 + blockIdx.x] = Ps[0][1][tid] + Ps[1][1][tid];
  }
}

// ---------- W2: BN finalize prologue + fused BN/ReLU A-staging + residual. grid (64,2)
__global__ __launch_bounds__(256) void gemm_w2(
    const float* __restrict__ hbuf, const short* __restrict__ w2t,
    const float* __restrict__ b2_, const float* __restrict__ psum,
    const float* __restrict__ psq, const float* __restrict__ g,
    const float* __restrict__ be, float* __restrict__ xd, short* __restrict__ xb) {
  __shared__ short SM[2 * 4096 + 2 * 8192];
  __shared__ float s_scale[512], s_shift[512];
  short* As = SM;
  short* Bs = SM + 8192;
  const int rb = blockIdx.x * 64, cb = blockIdx.y * 128;
  const int str = blockIdx.x >> 5;
  GEMM_IDS;
#pragma unroll
  for (int cc = 0; cc < 2; ++cc) {
    int c = tid + cc * 256;
    float sum = 0.f, sq = 0.f;
#pragma unroll
    for (int g4 = 0; g4 < 8; ++g4) {
      float4 a  = *(const float4*)&psum[(size_t)c * 64 + str * 32 + g4 * 4];
      float4 bq = *(const float4*)&psq [(size_t)c * 64 + str * 32 + g4 * 4];
      sum += a.x + a.y + a.z + a.w;
      sq  += bq.x + bq.y + bq.z + bq.w;
    }
    float mean = sum * (1.f / 2048.f);
    float var = sq * (1.f / 2048.f) - mean * mean;
    float rstd = rsqrtf(var + 1e-5f);
    float gs = g[c] * rstd;
    s_scale[c] = gs;
    s_shift[c] = be[c] - mean * gs;
  }
  __syncthreads();   // s_scale ready

  const int p = tid & 7, ar = tid >> 3;     // A-staging ids

#define W2_STAGE_A(s, buf)                                                         \
  {                                                                                \
    int k0 = (s) * 64;                                                             \
    _Pragma("unroll") for (int half = 0; half < 2; ++half) {                       \
      int row = ar + half * 32;                                                    \
      int cs = k0 + ((p ^ (row & 7)) * 8);                                         \
      float4 h0 = *(const float4*)&hbuf[(size_t)(rb + row) * 512 + cs];            \
      float4 h1 = *(const float4*)&hbuf[(size_t)(rb + row) * 512 + cs + 4];        \
      float4 sc0 = *(const float4*)&s_scale[cs];                                   \
      float4 sc1 = *(const float4*)&s_scale[cs + 4];                               \
      float4 sh0 = *(const float4*)&s_shift[cs];                                   \
      float4 sh1 = *(const float4*)&s_shift[cs + 4];                               \
      uint4 pk;                                                                    \
      pk.x = pack2(fmaxf(h0.x * sc0.x + sh0.x, 0.f), fmaxf(h0.y * sc0.y + sh0.y, 0.f)); \
      pk.y = pack2(fmaxf(h0.z * sc0.z + sh0.z, 0.f), fmaxf(h0.w * sc0.w + sh0.w, 0.f)); \
      pk.z = pack2(fmaxf(h1.x * sc1.x + sh1.x, 0.f), fmaxf(h1.y * sc1.y + sh1.y, 0.f)); \
      pk.w = pack2(fmaxf(h1.z * sc1.z + sh1.z, 0.f), fmaxf(h1.w * sc1.w + sh1.w, 0.f)); \
      *(uint4*)&As[(buf) * 4096 + row * 64 + p * 8] = pk;                          \
    }                                                                              \
  }
#define W2_STAGE_B(s, buf)                                                         \
  {                                                                                \
    int k0 = (s) * 64;                                                             \
    _Pragma("unroll") for (int i = 0; i < 4; ++i)                                  \
      gl2lds16(&w2t[(size_t)(cb + i * 32 + w * 8 + lr) * 512 + k0 + lcs],          \
               &Bs[(buf) * 8192 + (i * 32 + w * 8) * 64]);                         \
  }

  W2_STAGE_A(0, 0);
  W2_STAGE_B(0, 0);
  __syncthreads();
  for (int s = 0; s < 8; ++s) {
    int buf = s & 1;
    if (s < 7) W2_STAGE_B(s + 1, buf ^ 1);
    mfma_step_sw(&As[buf * 4096], &Bs[buf * 8192], wy, wx, quad, l16, acc);
    if (s < 7) W2_STAGE_A(s + 1, buf ^ 1);
    __syncthreads();
  }
#pragma unroll
  for (int mi = 0; mi < 2; ++mi)
#pragma unroll
    for (int ni = 0; ni < 4; ++ni) {
      int col = cb + wx * 64 + ni * 16 + l16;
      float bc = b2_[col];
#pragma unroll
      for (int reg = 0; reg < 4; ++reg) {
        int row = rb + wy * 32 + mi * 16 + quad * 4 + reg;
        float r = xd[(size_t)row * 256 + col] + acc[mi][ni][reg] + bc;
        xd[(size_t)row * 256 + col] = r;
        xb[(size_t)row * 256 + col] = f2b(r);
      }
    }
}

extern "C" void kernel_launch(void* const* d_in, const int* in_sizes, int n_in,
                              void* d_out, int out_size, void* d_ws, size_t ws_size,
                              hipStream_t stream) {
  (void)in_sizes; (void)n_in; (void)out_size;
  const float* desc = (const float*)d_in[0];
  const int*   mask = (const int*)d_in[1];
  const float* qw = (const float*)d_in[2];
  const float* qb = (const float*)d_in[3];
  const float* kw = (const float*)d_in[4];
  const float* kb = (const float*)d_in[5];
  const float* vw = (const float*)d_in[6];
  const float* vb = (const float*)d_in[7];
  const float* ow = (const float*)d_in[8];
  const float* ob = (const float*)d_in[9];
  const float* w1 = (const float*)d_in[10];
  const float* b1 = (const float*)d_in[11];
  const float* bn_g = (const float*)d_in[12];
  const float* bn_b = (const float*)d_in[13];
  const float* w2 = (const float*)d_in[14];
  const float* b2 = (const float*)d_in[15];
  float* out = (float*)d_out;

  char* base = (char*)d_ws;
  float* xd    = (float*)(base);                  // [0,4) MB
  float* hbuf  = (float*)(base + (4u << 20));     // [4,12) MB
  short* xb    = (short*)(base + (12u << 20));
  short* qb16  = (short*)(base + (14u << 20));
  short* kb16  = (short*)(base + (16u << 20));
  short* vTb   = (short*)(base + (18u << 20));
  short* attnb = (short*)(base + (20u << 20));
  float* psum  = (float*)(base + (22u << 20));    // [512][64]
  float* psq   = psum + 32768;
  float* beff  = psq + 32768;                     // up to 18*512 fp32
  short* wbuf  = (short*)(base + (24u << 20));    // 18*655360 shorts = 23.6 MB

  const int hoist = (ws_size >= ((size_t)48 << 20)) ? 1 : 0;

  swap_copy_in<<<1024, 256, 0, stream>>>(desc, xd, xb);
  if (hoist) {
    wconv<<<112 * 18, 256, 0, stream>>>(qw, kw, vw, w1, w2, wbuf, 0);
    wfuse<<<32 * 18, 256, 0, stream>>>(ow, w1, wbuf, 0);
    bfuse<<<18, 256, 0, stream>>>(ob, w1, b1, beff, 0);
  }

  for (int i = 0; i < 18; ++i) {
    int cross = i & 1;
    short* wb = hoist ? wbuf + (size_t)i * 655360 : wbuf;
    float* beffL = hoist ? beff + (size_t)i * 512 : beff;
    if (!hoist) {
      wconv<<<112, 256, 0, stream>>>(qw, kw, vw, w1, w2, wbuf, i);
      wfuse<<<32, 256, 0, stream>>>(ow, w1, wbuf, i);
      bfuse<<<1, 256, 0, stream>>>(ob, w1, b1, beff, i);
    }

    gemm_qkv<<<dim3(64, 6), 256, 0, stream>>>(
        xb, wb, qb + (size_t)i * 256, kb + (size_t)i * 256, vb + (size_t)i * 256,
        qb16, kb16, vTb, cross);
    attn_mfma<<<dim3(16, 16), 256, 0, stream>>>(qb16, kb16, vTb, mask, attnb, cross);
    gemm_w1<<<dim3(64, 4), 256, 0, stream>>>(xb, attnb, wb + 262144, beffL,
                                             hbuf, psum, psq);
    gemm_w2<<<dim3(64, 2), 256, 0, stream>>>(hbuf, wb + 524288,
                                             b2 + (size_t)i * 256, psum, psq,
                                             bn_g + (size_t)i * 512,
                                             bn_b + (size_t)i * 512, xd, xb);
  }

  swap_copy_out<<<1024, 256, 0, stream>>>(xd, out);
}